// Round 5
// baseline (51.002 us; speedup 1.0000x reference)
//
#include <hip/hip_runtime.h>
#include <math.h>

#define DN 16
#define DNZ 16
#define DOUT 8
#define DH 32
#define DB 16384
#define RINV 10.0f
#define DPSI 24  // NZ+OUT

// ---- LDS layout (floats); second-layer weights TRANSPOSED [k][m] ----
#define O_WT1    0      // 32x16
#define O_WT2T   512    // 32x16
#define O_Wtau1  1024   // 32x16
#define O_Wtau2T 1536   // 32x16
#define O_Wh1    2048   // 32x16
#define O_Wh2T   2560   // 32x8
#define O_Wpsi1  2816   // 32x24
#define O_Wpsi2T 3584   // 32x16
#define O_Wf1    4096   // 32x16
#define O_Wf2T   4608   // 32x16
#define O_WP     5120   // 16x16
#define O_bT1    5376
#define O_btau1  5408
#define O_bh1    5440
#define O_bpsi1  5472
#define O_bf1    5504
#define LDS_FLOATS 5536

// tanh(x) = 1 - 2/(1+exp(2x))
__device__ __forceinline__ float ftanh(float v) {
  float ex = __builtin_amdgcn_exp2f(v * 2.885390081777926815f);
  float r = __builtin_amdgcn_rcpf(1.0f + ex);
  return fmaf(-2.0f, r, 1.0f);
}

// quad_perm DPP: xor1 = [1,0,3,2] = 0xB1, xor2 = [2,3,0,1] = 0x4E
__device__ __forceinline__ float qxor1(float v) {
  return __int_as_float(__builtin_amdgcn_mov_dpp(__float_as_int(v), 0xB1, 0xF, 0xF, true));
}
__device__ __forceinline__ float qxor2(float v) {
  return __int_as_float(__builtin_amdgcn_mov_dpp(__float_as_int(v), 0x4E, 0xF, 0xF, true));
}
__device__ __forceinline__ float qsum(float v) {
  v += qxor1(v);
  v += qxor2(v);
  return v;
}
// per-lane select of one of 4 registers by p (2 cndmask levels, no scratch)
__device__ __forceinline__ float qsel(float v0, float v1, float v2, float v3, int p) {
  float a = (p & 1) ? v1 : v0;
  float b = (p & 1) ? v3 : v2;
  return (p & 2) ? b : a;
}

// 4-accumulator dot (dep depth ~6 instead of 16)
__device__ __forceinline__ float dot16(const float* __restrict__ W, const float* __restrict__ v) {
  float a0 = 0.f, a1 = 0.f, a2 = 0.f, a3 = 0.f;
#pragma unroll
  for (int j = 0; j < 4; ++j) {
    a0 = fmaf(W[j], v[j], a0);
    a1 = fmaf(W[j + 4], v[j + 4], a1);
    a2 = fmaf(W[j + 8], v[j + 8], a2);
    a3 = fmaf(W[j + 12], v[j + 12], a3);
  }
  return (a0 + a1) + (a2 + a3);
}
__device__ __forceinline__ float dot8(const float* __restrict__ W, const float* __restrict__ v) {
  float a0 = 0.f, a1 = 0.f;
#pragma unroll
  for (int j = 0; j < 4; ++j) {
    a0 = fmaf(W[j], v[j], a0);
    a1 = fmaf(W[j + 4], v[j + 4], a1);
  }
  return a0 + a1;
}

__global__ __launch_bounds__(256, 1) void loss_kernel(
    const float* __restrict__ x_batch, const float* __restrict__ e_batch,
    const float* __restrict__ Wf1, const float* __restrict__ bf1, const float* __restrict__ Wf2,
    const float* __restrict__ Wh1, const float* __restrict__ bh1, const float* __restrict__ Wh2,
    const float* __restrict__ WT1, const float* __restrict__ bT1, const float* __restrict__ WT2,
    const float* __restrict__ Wtau1, const float* __restrict__ btau1, const float* __restrict__ Wtau2,
    const float* __restrict__ Wpsi1, const float* __restrict__ bpsi1, const float* __restrict__ Wpsi2,
    const float* __restrict__ WP,
    float* __restrict__ out) {
  __shared__ float sW[LDS_FLOATS];
  __shared__ float wsum[4];
  const int tid = threadIdx.x;

  // ---- staging (256 threads) ----
  {
#pragma unroll
    for (int r = 0; r < 2; ++r) sW[O_WT1 + r * 256 + tid] = WT1[r * 256 + tid];
#pragma unroll
    for (int r = 0; r < 2; ++r) sW[O_Wtau1 + r * 256 + tid] = Wtau1[r * 256 + tid];
#pragma unroll
    for (int r = 0; r < 2; ++r) sW[O_Wh1 + r * 256 + tid] = Wh1[r * 256 + tid];
#pragma unroll
    for (int r = 0; r < 3; ++r) sW[O_Wpsi1 + r * 256 + tid] = Wpsi1[r * 256 + tid];
#pragma unroll
    for (int r = 0; r < 2; ++r) sW[O_Wf1 + r * 256 + tid] = Wf1[r * 256 + tid];
    sW[O_WP + tid] = WP[tid];
    // transposed: global (M,32) idx -> [k][m]
#pragma unroll
    for (int r = 0; r < 2; ++r) {
      int idx = r * 256 + tid; int j = idx >> 5, k = idx & 31;
      sW[O_WT2T + k * DNZ + j] = WT2[idx];
    }
#pragma unroll
    for (int r = 0; r < 2; ++r) {
      int idx = r * 256 + tid; int j = idx >> 5, k = idx & 31;
      sW[O_Wtau2T + k * DN + j] = Wtau2[idx];
    }
#pragma unroll
    for (int r = 0; r < 2; ++r) {
      int idx = r * 256 + tid; int j = idx >> 5, k = idx & 31;
      sW[O_Wpsi2T + k * DNZ + j] = Wpsi2[idx];
    }
#pragma unroll
    for (int r = 0; r < 2; ++r) {
      int idx = r * 256 + tid; int j = idx >> 5, k = idx & 31;
      sW[O_Wf2T + k * DN + j] = Wf2[idx];
    }
    { int o = tid >> 5, k = tid & 31; sW[O_Wh2T + k * DOUT + o] = Wh2[tid]; }
    if (tid < 32) {
      sW[O_bT1 + tid] = bT1[tid];
      sW[O_btau1 + tid] = btau1[tid];
      sW[O_bh1 + tid] = bh1[tid];
      sW[O_bpsi1 + tid] = bpsi1[tid];
      sW[O_bf1 + tid] = bf1[tid];
    }
  }
  __syncthreads();

  const int p = tid & 3;                          // lane in quad
  const int sidx = blockIdx.x * 64 + (tid >> 2);  // sample

  // ---- load sample (replicated across quad; cache-served) ----
  float x[DN], e[DNZ];
  {
    const float4* xp = reinterpret_cast<const float4*>(x_batch + (size_t)sidx * DN);
    const float4* ep = reinterpret_cast<const float4*>(e_batch + (size_t)sidx * DNZ);
#pragma unroll
    for (int q = 0; q < 4; ++q) {
      float4 vx = xp[q], ve = ep[q];
      x[4 * q + 0] = vx.x; x[4 * q + 1] = vx.y; x[4 * q + 2] = vx.z; x[4 * q + 3] = vx.w;
      e[4 * q + 0] = ve.x; e[4 * q + 1] = ve.y; e[4 * q + 2] = ve.z; e[4 * q + 3] = ve.w;
    }
  }

  // ---- A: z = T(x) + e ----
  float z[DNZ];
#pragma unroll
  for (int j = 0; j < DNZ; ++j) z[j] = 0.f;
#pragma unroll
  for (int kk = 0; kk < 8; ++kk) {
    const int k = 4 * kk + p;
    float t = ftanh(dot16(sW + O_WT1 + k * DN, x) + sW[O_bT1 + k]);
    const float* Ct = sW + O_WT2T + k * DNZ;
#pragma unroll
    for (int j = 0; j < DNZ; ++j) z[j] = fmaf(Ct[j], t, z[j]);
  }
#pragma unroll
  for (int j = 0; j < DNZ; ++j) z[j] = qsum(z[j]) + e[j];

  // ---- B: xh = tau(z); x -> diff ----
  float xh[DN];
#pragma unroll
  for (int n = 0; n < DN; ++n) xh[n] = 0.f;
#pragma unroll
  for (int kk = 0; kk < 8; ++kk) {
    const int k = 4 * kk + p;
    float t = ftanh(dot16(sW + O_Wtau1 + k * DNZ, z) + sW[O_btau1 + k]);
    const float* Ct = sW + O_Wtau2T + k * DN;
#pragma unroll
    for (int n = 0; n < DN; ++n) xh[n] = fmaf(Ct[n], t, xh[n]);
  }
#pragma unroll
  for (int n = 0; n < DN; ++n) { xh[n] = qsum(xh[n]); x[n] -= xh[n]; }

  // ---- C: yh + dth (lane-owned) ----
  float yh[DOUT];
#pragma unroll
  for (int o = 0; o < DOUT; ++o) yh[o] = 0.f;
  float dth[8];
#pragma unroll
  for (int kk = 0; kk < 8; ++kk) {
    const int k = 4 * kk + p;
    float t = ftanh(dot16(sW + O_Wh1 + k * DN, xh) + sW[O_bh1 + k]);
    dth[kk] = 1.f - t * t;
    const float* Ct = sW + O_Wh2T + k * DOUT;
#pragma unroll
    for (int o = 0; o < DOUT; ++o) yh[o] = fmaf(Ct[o], t, yh[o]);
  }
#pragma unroll
  for (int o = 0; o < DOUT; ++o) yh[o] = qsum(yh[o]);

  // ---- D: w8 = RINV * Wh2 @ (dth ∘ (Wh1 @ diff)) ----
  float w8[DOUT];
#pragma unroll
  for (int o = 0; o < DOUT; ++o) w8[o] = 0.f;
#pragma unroll
  for (int kk = 0; kk < 8; ++kk) {
    const int k = 4 * kk + p;
    float g = dot16(sW + O_Wh1 + k * DN, x) * dth[kk];
    const float* Ct = sW + O_Wh2T + k * DOUT;
#pragma unroll
    for (int o = 0; o < DOUT; ++o) w8[o] = fmaf(Ct[o], g, w8[o]);
  }
#pragma unroll
  for (int o = 0; o < DOUT; ++o) w8[o] = qsum(w8[o]) * RINV;

  // ---- E: u = Wh1^T @ (dth ∘ (Wh2^T @ w8)) ----
  float u[DN];
#pragma unroll
  for (int n = 0; n < DN; ++n) u[n] = 0.f;
#pragma unroll
  for (int kk = 0; kk < 8; ++kk) {
    const int k = 4 * kk + p;
    float g = dot8(sW + O_Wh2T + k * DOUT, w8) * dth[kk];
    const float* Wr = sW + O_Wh1 + k * DN;
#pragma unroll
    for (int n = 0; n < DN; ++n) u[n] = fmaf(Wr[n], g, u[n]);
  }
#pragma unroll
  for (int n = 0; n < DN; ++n) u[n] = qsum(u[n]);

  // ---- F: sv (lane-owned n = 4nn+p), sdot; u gathered via qsel (no scratch) ----
  float sv[4], usel[4];
  float sdp = 0.f;
#pragma unroll
  for (int nn = 0; nn < 4; ++nn) {
    const int n = 4 * nn + p;
    sv[nn] = ftanh(dot16(sW + O_WP + n * DN, xh));
    usel[nn] = qsel(u[4 * nn + 0], u[4 * nn + 1], u[4 * nn + 2], u[4 * nn + 3], p);
    sdp = fmaf(sv[nn], usel[nn], sdp);
  }
  const float sdot = qsum(sdp);

  // ---- G: Tx = T(xh) ----
  float Tx[DNZ];
#pragma unroll
  for (int j = 0; j < DNZ; ++j) Tx[j] = 0.f;
#pragma unroll
  for (int kk = 0; kk < 8; ++kk) {
    const int k = 4 * kk + p;
    float t = ftanh(dot16(sW + O_WT1 + k * DN, xh) + sW[O_bT1 + k]);
    const float* Ct = sW + O_WT2T + k * DNZ;
#pragma unroll
    for (int j = 0; j < DNZ; ++j) Tx[j] = fmaf(Ct[j], t, Tx[j]);
  }
#pragma unroll
  for (int j = 0; j < DNZ; ++j) Tx[j] = qsum(Tx[j]);

  // ---- H: phi = psi(Tx,yh); jph = Jphi @ e ----
  float phi[DNZ], jph[DNZ];
#pragma unroll
  for (int j = 0; j < DNZ; ++j) { phi[j] = 0.f; jph[j] = 0.f; }
#pragma unroll
  for (int kk = 0; kk < 8; ++kk) {
    const int k = 4 * kk + p;
    const float* Wr = sW + O_Wpsi1 + k * DPSI;
    float t = ftanh(dot16(Wr, Tx) + dot8(Wr + DNZ, yh) + sW[O_bpsi1 + k]);
    float d = 1.f - t * t;
    float g = d * dot16(Wr, e);
    const float* Ct = sW + O_Wpsi2T + k * DNZ;
#pragma unroll
    for (int j = 0; j < DNZ; ++j) {
      phi[j] = fmaf(Ct[j], t, phi[j]);
      jph[j] = fmaf(Ct[j], g, jph[j]);
    }
  }
#pragma unroll
  for (int j = 0; j < DNZ; ++j) { phi[j] = qsum(phi[j]); jph[j] = qsum(jph[j]); }

  // ---- I: t2e = Htau@e + Jtau@jph (partial); jte = Jtau@e (reduced) ----
  float t2e[DN], jte[DN];
#pragma unroll
  for (int n = 0; n < DN; ++n) { t2e[n] = 0.f; jte[n] = 0.f; }
#pragma unroll
  for (int kk = 0; kk < 8; ++kk) {
    const int k = 4 * kk + p;
    const float* Wr = sW + O_Wtau1 + k * DNZ;
    float a = dot16(Wr, Tx) + sW[O_btau1 + k];
    float wp = dot16(Wr, phi);
    float v = dot16(Wr, e);
    float q = dot16(Wr, jph);
    float t = ftanh(a);
    float d = 1.f - t * t;
    float c = -2.f * t * d * wp;
    float g1 = fmaf(c, v, d * q);
    float g2 = d * v;
    const float* Ct = sW + O_Wtau2T + k * DN;
#pragma unroll
    for (int n = 0; n < DN; ++n) {
      t2e[n] = fmaf(Ct[n], g1, t2e[n]);
      jte[n] = fmaf(Ct[n], g2, jte[n]);
    }
  }
#pragma unroll
  for (int n = 0; n < DN; ++n) jte[n] = qsum(jte[n]);  // t2e stays partial

  // ---- J: t2e -= Jf @ jte (accumulate into partials, then reduce) ----
#pragma unroll
  for (int kk = 0; kk < 8; ++kk) {
    const int k = 4 * kk + p;
    const float* Wr = sW + O_Wf1 + k * DN;
    float a = dot16(Wr, xh) + sW[O_bf1 + k];
    float gj = dot16(Wr, jte);
    float t = ftanh(a);
    float g = (1.f - t * t) * gj;
    const float* Ct = sW + O_Wf2T + k * DN;
#pragma unroll
    for (int n = 0; n < DN; ++n) t2e[n] = fmaf(-Ct[n], g, t2e[n]);
  }
#pragma unroll
  for (int n = 0; n < DN; ++n) t2e[n] = qsum(t2e[n]);

  // ---- K: loss (lane-owned n's via qsel, quad reduce) ----
  float ss = 0.f;
#pragma unroll
  for (int nn = 0; nn < 4; ++nn) {
    float tsel = qsel(t2e[4 * nn + 0], t2e[4 * nn + 1], t2e[4 * nn + 2], t2e[4 * nn + 3], p);
    float r = fmaf(sv[nn], sdot, usel[nn]) - tsel;
    ss = fmaf(r, r, ss);
  }
  ss = qsum(ss);
  float loss = sqrtf(ss);  // same on all 4 quad lanes

  // wave reduce across quads: xor offsets >=4 pair distinct quads, so each
  // quad's loss is counted EXACTLY ONCE -> wave sum = 16 sample losses.
#pragma unroll
  for (int off = 4; off < 64; off <<= 1) loss += __shfl_xor(loss, off);

  // block reduce: 4 waves (64 samples) -> one atomic per block
  if ((tid & 63) == 0) wsum[tid >> 6] = loss;
  __syncthreads();
  if (tid == 0)
    atomicAdd(out, (wsum[0] + wsum[1] + wsum[2] + wsum[3]) * (1.0f / (float)DB));
}

extern "C" void kernel_launch(void* const* d_in, const int* in_sizes, int n_in,
                              void* d_out, int out_size, void* d_ws, size_t ws_size,
                              hipStream_t stream) {
  const float* x_batch = (const float*)d_in[0];
  const float* e_batch = (const float*)d_in[1];
  const float* Wf1 = (const float*)d_in[2];
  const float* bf1 = (const float*)d_in[3];
  const float* Wf2 = (const float*)d_in[4];
  const float* Wh1 = (const float*)d_in[5];
  const float* bh1 = (const float*)d_in[6];
  const float* Wh2 = (const float*)d_in[7];
  const float* WT1 = (const float*)d_in[8];
  const float* bT1 = (const float*)d_in[9];
  const float* WT2 = (const float*)d_in[10];
  const float* Wtau1 = (const float*)d_in[11];
  const float* btau1 = (const float*)d_in[12];
  const float* Wtau2 = (const float*)d_in[13];
  const float* Wpsi1 = (const float*)d_in[14];
  const float* bpsi1 = (const float*)d_in[15];
  const float* Wpsi2 = (const float*)d_in[16];
  const float* WP = (const float*)d_in[17];

  hipMemsetAsync(d_out, 0, sizeof(float), stream);
  loss_kernel<<<DB / 64, 256, 0, stream>>>(
      x_batch, e_batch, Wf1, bf1, Wf2, Wh1, bh1, Wh2, WT1, bT1, WT2,
      Wtau1, btau1, Wtau2, Wpsi1, bpsi1, Wpsi2, WP, (float*)d_out);
}

// Round 6
// 29.571 us; speedup vs baseline: 1.7247x; 1.7247x over previous
//
#include <hip/hip_runtime.h>
#include <math.h>

#define DN 16
#define DNZ 16
#define DOUT 8
#define DH 32
#define DB 16384
#define RINV 10.0f
#define DPSI 24  // NZ+OUT

// ---- LDS layout (floats); second-layer weights TRANSPOSED [k][m] ----
#define O_WT1    0      // 32x16
#define O_WT2T   512    // 32x16
#define O_Wtau1  1024   // 32x16
#define O_Wtau2T 1536   // 32x16
#define O_Wh1    2048   // 32x16
#define O_Wh2T   2560   // 32x8
#define O_Wpsi1  2816   // 32x24
#define O_Wpsi2T 3584   // 32x16
#define O_Wf1    4096   // 32x16
#define O_Wf2T   4608   // 32x16
#define O_WP     5120   // 16x16
#define O_bT1    5376
#define O_btau1  5408
#define O_bh1    5440
#define O_bpsi1  5472
#define O_bf1    5504
#define LDS_FLOATS 5536

// tanh(x) = 1 - 2/(1+exp(2x))
__device__ __forceinline__ float ftanh(float v) {
  float ex = __builtin_amdgcn_exp2f(v * 2.885390081777926815f);
  float r = __builtin_amdgcn_rcpf(1.0f + ex);
  return fmaf(-2.0f, r, 1.0f);
}

// quad_perm DPP: xor1 = [1,0,3,2] = 0xB1, xor2 = [2,3,0,1] = 0x4E
__device__ __forceinline__ float qxor1(float v) {
  return __int_as_float(__builtin_amdgcn_mov_dpp(__float_as_int(v), 0xB1, 0xF, 0xF, true));
}
__device__ __forceinline__ float qxor2(float v) {
  return __int_as_float(__builtin_amdgcn_mov_dpp(__float_as_int(v), 0x4E, 0xF, 0xF, true));
}
__device__ __forceinline__ float qsum(float v) {
  v += qxor1(v);
  v += qxor2(v);
  return v;
}
// per-lane select of one of 4 registers by p (2 cndmask levels, no scratch)
__device__ __forceinline__ float qsel(float v0, float v1, float v2, float v3, int p) {
  float a = (p & 1) ? v1 : v0;
  float b = (p & 1) ? v3 : v2;
  return (p & 2) ? b : a;
}

// 4-accumulator dot (dep depth ~6 instead of 16)
__device__ __forceinline__ float dot16(const float* __restrict__ W, const float* __restrict__ v) {
  float a0 = 0.f, a1 = 0.f, a2 = 0.f, a3 = 0.f;
#pragma unroll
  for (int j = 0; j < 4; ++j) {
    a0 = fmaf(W[j], v[j], a0);
    a1 = fmaf(W[j + 4], v[j + 4], a1);
    a2 = fmaf(W[j + 8], v[j + 8], a2);
    a3 = fmaf(W[j + 12], v[j + 12], a3);
  }
  return (a0 + a1) + (a2 + a3);
}
__device__ __forceinline__ float dot8(const float* __restrict__ W, const float* __restrict__ v) {
  float a0 = 0.f, a1 = 0.f;
#pragma unroll
  for (int j = 0; j < 4; ++j) {
    a0 = fmaf(W[j], v[j], a0);
    a1 = fmaf(W[j + 4], v[j + 4], a1);
  }
  return a0 + a1;
}

__global__ __launch_bounds__(256, 1) void loss_kernel(
    const float* __restrict__ x_batch, const float* __restrict__ e_batch,
    const float* __restrict__ Wf1, const float* __restrict__ bf1, const float* __restrict__ Wf2,
    const float* __restrict__ Wh1, const float* __restrict__ bh1, const float* __restrict__ Wh2,
    const float* __restrict__ WT1, const float* __restrict__ bT1, const float* __restrict__ WT2,
    const float* __restrict__ Wtau1, const float* __restrict__ btau1, const float* __restrict__ Wtau2,
    const float* __restrict__ Wpsi1, const float* __restrict__ bpsi1, const float* __restrict__ Wpsi2,
    const float* __restrict__ WP,
    float* __restrict__ out) {
  __shared__ float sW[LDS_FLOATS];
  __shared__ float wsum[4];
  const int tid = threadIdx.x;

  // ---- staging (256 threads) ----
  {
#pragma unroll
    for (int r = 0; r < 2; ++r) sW[O_WT1 + r * 256 + tid] = WT1[r * 256 + tid];
#pragma unroll
    for (int r = 0; r < 2; ++r) sW[O_Wtau1 + r * 256 + tid] = Wtau1[r * 256 + tid];
#pragma unroll
    for (int r = 0; r < 2; ++r) sW[O_Wh1 + r * 256 + tid] = Wh1[r * 256 + tid];
#pragma unroll
    for (int r = 0; r < 3; ++r) sW[O_Wpsi1 + r * 256 + tid] = Wpsi1[r * 256 + tid];
#pragma unroll
    for (int r = 0; r < 2; ++r) sW[O_Wf1 + r * 256 + tid] = Wf1[r * 256 + tid];
    sW[O_WP + tid] = WP[tid];
    // transposed: global (M,32) idx -> [k][m]
#pragma unroll
    for (int r = 0; r < 2; ++r) {
      int idx = r * 256 + tid; int j = idx >> 5, k = idx & 31;
      sW[O_WT2T + k * DNZ + j] = WT2[idx];
    }
#pragma unroll
    for (int r = 0; r < 2; ++r) {
      int idx = r * 256 + tid; int j = idx >> 5, k = idx & 31;
      sW[O_Wtau2T + k * DN + j] = Wtau2[idx];
    }
#pragma unroll
    for (int r = 0; r < 2; ++r) {
      int idx = r * 256 + tid; int j = idx >> 5, k = idx & 31;
      sW[O_Wpsi2T + k * DNZ + j] = Wpsi2[idx];
    }
#pragma unroll
    for (int r = 0; r < 2; ++r) {
      int idx = r * 256 + tid; int j = idx >> 5, k = idx & 31;
      sW[O_Wf2T + k * DN + j] = Wf2[idx];
    }
    { int o = tid >> 5, k = tid & 31; sW[O_Wh2T + k * DOUT + o] = Wh2[tid]; }
    if (tid < 32) {
      sW[O_bT1 + tid] = bT1[tid];
      sW[O_btau1 + tid] = btau1[tid];
      sW[O_bh1 + tid] = bh1[tid];
      sW[O_bpsi1 + tid] = bpsi1[tid];
      sW[O_bf1 + tid] = bf1[tid];
    }
  }
  __syncthreads();

  const int p = tid & 3;                          // lane in quad
  const int sidx = blockIdx.x * 64 + (tid >> 2);  // sample

  // ---- load sample (replicated across quad; cache-served) ----
  float x[DN], e[DNZ];
  {
    const float4* xp = reinterpret_cast<const float4*>(x_batch + (size_t)sidx * DN);
    const float4* ep = reinterpret_cast<const float4*>(e_batch + (size_t)sidx * DNZ);
#pragma unroll
    for (int q = 0; q < 4; ++q) {
      float4 vx = xp[q], ve = ep[q];
      x[4 * q + 0] = vx.x; x[4 * q + 1] = vx.y; x[4 * q + 2] = vx.z; x[4 * q + 3] = vx.w;
      e[4 * q + 0] = ve.x; e[4 * q + 1] = ve.y; e[4 * q + 2] = ve.z; e[4 * q + 3] = ve.w;
    }
  }

  // ---- A: z = T(x) + e ----
  float z[DNZ];
#pragma unroll
  for (int j = 0; j < DNZ; ++j) z[j] = 0.f;
#pragma unroll 2
  for (int kk = 0; kk < 8; ++kk) {
    const int k = 4 * kk + p;
    float t = ftanh(dot16(sW + O_WT1 + k * DN, x) + sW[O_bT1 + k]);
    const float* Ct = sW + O_WT2T + k * DNZ;
#pragma unroll
    for (int j = 0; j < DNZ; ++j) z[j] = fmaf(Ct[j], t, z[j]);
  }
#pragma unroll
  for (int j = 0; j < DNZ; ++j) z[j] = qsum(z[j]) + e[j];

  // ---- B: xh = tau(z); x -> diff ----
  float xh[DN];
#pragma unroll
  for (int n = 0; n < DN; ++n) xh[n] = 0.f;
#pragma unroll 2
  for (int kk = 0; kk < 8; ++kk) {
    const int k = 4 * kk + p;
    float t = ftanh(dot16(sW + O_Wtau1 + k * DNZ, z) + sW[O_btau1 + k]);
    const float* Ct = sW + O_Wtau2T + k * DN;
#pragma unroll
    for (int n = 0; n < DN; ++n) xh[n] = fmaf(Ct[n], t, xh[n]);
  }
#pragma unroll
  for (int n = 0; n < DN; ++n) { xh[n] = qsum(xh[n]); x[n] -= xh[n]; }

  // ---- C: yh + dth (lane-owned) ----
  float yh[DOUT];
#pragma unroll
  for (int o = 0; o < DOUT; ++o) yh[o] = 0.f;
  float dth[8];
#pragma unroll 2
  for (int kk = 0; kk < 8; ++kk) {
    const int k = 4 * kk + p;
    float t = ftanh(dot16(sW + O_Wh1 + k * DN, xh) + sW[O_bh1 + k]);
    dth[kk] = 1.f - t * t;
    const float* Ct = sW + O_Wh2T + k * DOUT;
#pragma unroll
    for (int o = 0; o < DOUT; ++o) yh[o] = fmaf(Ct[o], t, yh[o]);
  }
#pragma unroll
  for (int o = 0; o < DOUT; ++o) yh[o] = qsum(yh[o]);

  // ---- D: w8 = RINV * Wh2 @ (dth ∘ (Wh1 @ diff)) ----
  float w8[DOUT];
#pragma unroll
  for (int o = 0; o < DOUT; ++o) w8[o] = 0.f;
#pragma unroll 2
  for (int kk = 0; kk < 8; ++kk) {
    const int k = 4 * kk + p;
    float g = dot16(sW + O_Wh1 + k * DN, x) * dth[kk];
    const float* Ct = sW + O_Wh2T + k * DOUT;
#pragma unroll
    for (int o = 0; o < DOUT; ++o) w8[o] = fmaf(Ct[o], g, w8[o]);
  }
#pragma unroll
  for (int o = 0; o < DOUT; ++o) w8[o] = qsum(w8[o]) * RINV;

  // ---- E: u = Wh1^T @ (dth ∘ (Wh2^T @ w8)) ----
  float u[DN];
#pragma unroll
  for (int n = 0; n < DN; ++n) u[n] = 0.f;
#pragma unroll 2
  for (int kk = 0; kk < 8; ++kk) {
    const int k = 4 * kk + p;
    float g = dot8(sW + O_Wh2T + k * DOUT, w8) * dth[kk];
    const float* Wr = sW + O_Wh1 + k * DN;
#pragma unroll
    for (int n = 0; n < DN; ++n) u[n] = fmaf(Wr[n], g, u[n]);
  }
#pragma unroll
  for (int n = 0; n < DN; ++n) u[n] = qsum(u[n]);

  // ---- F: sv (lane-owned n = 4nn+p), sdot; u gathered via qsel (no scratch) ----
  float sv[4], usel[4];
  float sdp = 0.f;
#pragma unroll 2
  for (int nn = 0; nn < 4; ++nn) {
    const int n = 4 * nn + p;
    sv[nn] = ftanh(dot16(sW + O_WP + n * DN, xh));
    usel[nn] = qsel(u[4 * nn + 0], u[4 * nn + 1], u[4 * nn + 2], u[4 * nn + 3], p);
    sdp = fmaf(sv[nn], usel[nn], sdp);
  }
  const float sdot = qsum(sdp);

  // ---- G: Tx = T(xh) ----
  float Tx[DNZ];
#pragma unroll
  for (int j = 0; j < DNZ; ++j) Tx[j] = 0.f;
#pragma unroll 2
  for (int kk = 0; kk < 8; ++kk) {
    const int k = 4 * kk + p;
    float t = ftanh(dot16(sW + O_WT1 + k * DN, xh) + sW[O_bT1 + k]);
    const float* Ct = sW + O_WT2T + k * DNZ;
#pragma unroll
    for (int j = 0; j < DNZ; ++j) Tx[j] = fmaf(Ct[j], t, Tx[j]);
  }
#pragma unroll
  for (int j = 0; j < DNZ; ++j) Tx[j] = qsum(Tx[j]);

  // ---- H: phi = psi(Tx,yh); jph = Jphi @ e ----
  float phi[DNZ], jph[DNZ];
#pragma unroll
  for (int j = 0; j < DNZ; ++j) { phi[j] = 0.f; jph[j] = 0.f; }
#pragma unroll 2
  for (int kk = 0; kk < 8; ++kk) {
    const int k = 4 * kk + p;
    const float* Wr = sW + O_Wpsi1 + k * DPSI;
    float t = ftanh(dot16(Wr, Tx) + dot8(Wr + DNZ, yh) + sW[O_bpsi1 + k]);
    float d = 1.f - t * t;
    float g = d * dot16(Wr, e);
    const float* Ct = sW + O_Wpsi2T + k * DNZ;
#pragma unroll
    for (int j = 0; j < DNZ; ++j) {
      phi[j] = fmaf(Ct[j], t, phi[j]);
      jph[j] = fmaf(Ct[j], g, jph[j]);
    }
  }
#pragma unroll
  for (int j = 0; j < DNZ; ++j) { phi[j] = qsum(phi[j]); jph[j] = qsum(jph[j]); }

  // ---- I: t2e = Htau@e + Jtau@jph (partial); jte = Jtau@e (reduced) ----
  float t2e[DN], jte[DN];
#pragma unroll
  for (int n = 0; n < DN; ++n) { t2e[n] = 0.f; jte[n] = 0.f; }
#pragma unroll 2
  for (int kk = 0; kk < 8; ++kk) {
    const int k = 4 * kk + p;
    const float* Wr = sW + O_Wtau1 + k * DNZ;
    float a = dot16(Wr, Tx) + sW[O_btau1 + k];
    float wp = dot16(Wr, phi);
    float v = dot16(Wr, e);
    float q = dot16(Wr, jph);
    float t = ftanh(a);
    float d = 1.f - t * t;
    float c = -2.f * t * d * wp;
    float g1 = fmaf(c, v, d * q);
    float g2 = d * v;
    const float* Ct = sW + O_Wtau2T + k * DN;
#pragma unroll
    for (int n = 0; n < DN; ++n) {
      t2e[n] = fmaf(Ct[n], g1, t2e[n]);
      jte[n] = fmaf(Ct[n], g2, jte[n]);
    }
  }
#pragma unroll
  for (int n = 0; n < DN; ++n) jte[n] = qsum(jte[n]);  // t2e stays partial

  // ---- J: t2e -= Jf @ jte (accumulate into partials, then reduce) ----
#pragma unroll 2
  for (int kk = 0; kk < 8; ++kk) {
    const int k = 4 * kk + p;
    const float* Wr = sW + O_Wf1 + k * DN;
    float a = dot16(Wr, xh) + sW[O_bf1 + k];
    float gj = dot16(Wr, jte);
    float t = ftanh(a);
    float g = (1.f - t * t) * gj;
    const float* Ct = sW + O_Wf2T + k * DN;
#pragma unroll
    for (int n = 0; n < DN; ++n) t2e[n] = fmaf(-Ct[n], g, t2e[n]);
  }
#pragma unroll
  for (int n = 0; n < DN; ++n) t2e[n] = qsum(t2e[n]);

  // ---- K: loss (lane-owned n's via qsel, quad reduce) ----
  float ss = 0.f;
#pragma unroll
  for (int nn = 0; nn < 4; ++nn) {
    float tsel = qsel(t2e[4 * nn + 0], t2e[4 * nn + 1], t2e[4 * nn + 2], t2e[4 * nn + 3], p);
    float r = fmaf(sv[nn], sdot, usel[nn]) - tsel;
    ss = fmaf(r, r, ss);
  }
  ss = qsum(ss);
  float loss = sqrtf(ss);  // same on all 4 quad lanes

  // wave reduce across quads: xor offsets >=4 pair distinct quads, so each
  // quad's loss is counted EXACTLY ONCE -> wave sum = 16 sample losses.
#pragma unroll
  for (int off = 4; off < 64; off <<= 1) loss += __shfl_xor(loss, off);

  // block reduce: 4 waves (64 samples) -> one atomic per block
  if ((tid & 63) == 0) wsum[tid >> 6] = loss;
  __syncthreads();
  if (tid == 0)
    atomicAdd(out, (wsum[0] + wsum[1] + wsum[2] + wsum[3]) * (1.0f / (float)DB));
}

extern "C" void kernel_launch(void* const* d_in, const int* in_sizes, int n_in,
                              void* d_out, int out_size, void* d_ws, size_t ws_size,
                              hipStream_t stream) {
  const float* x_batch = (const float*)d_in[0];
  const float* e_batch = (const float*)d_in[1];
  const float* Wf1 = (const float*)d_in[2];
  const float* bf1 = (const float*)d_in[3];
  const float* Wf2 = (const float*)d_in[4];
  const float* Wh1 = (const float*)d_in[5];
  const float* bh1 = (const float*)d_in[6];
  const float* Wh2 = (const float*)d_in[7];
  const float* WT1 = (const float*)d_in[8];
  const float* bT1 = (const float*)d_in[9];
  const float* WT2 = (const float*)d_in[10];
  const float* Wtau1 = (const float*)d_in[11];
  const float* btau1 = (const float*)d_in[12];
  const float* Wtau2 = (const float*)d_in[13];
  const float* Wpsi1 = (const float*)d_in[14];
  const float* bpsi1 = (const float*)d_in[15];
  const float* Wpsi2 = (const float*)d_in[16];
  const float* WP = (const float*)d_in[17];

  hipMemsetAsync(d_out, 0, sizeof(float), stream);
  loss_kernel<<<DB / 64, 256, 0, stream>>>(
      x_batch, e_batch, Wf1, bf1, Wf2, Wh1, bh1, Wh2, WT1, bT1, WT2,
      Wtau1, btau1, Wtau2, Wpsi1, bpsi1, Wpsi2, WP, (float*)d_out);
}

// Round 7
// 27.427 us; speedup vs baseline: 1.8596x; 1.0782x over previous
//
#include <hip/hip_runtime.h>
#include <math.h>

#define DN 16
#define DNZ 16
#define DOUT 8
#define DH 32
#define DB 16384
#define RINV 10.0f
#define DPSI 24  // NZ+OUT

// ---- LDS layout (floats); second-layer weights TRANSPOSED [k][m] ----
#define O_WT1    0      // 32x16
#define O_WT2T   512    // 32x16
#define O_Wtau1  1024   // 32x16
#define O_Wtau2T 1536   // 32x16
#define O_Wh1    2048   // 32x16
#define O_Wh2T   2560   // 32x8
#define O_Wpsi1  2816   // 32x24
#define O_Wpsi2T 3584   // 32x16
#define O_Wf1    4096   // 32x16
#define O_Wf2T   4608   // 32x16
#define O_WP     5120   // 16x16
#define O_bT1    5376
#define O_btau1  5408
#define O_bh1    5440
#define O_bpsi1  5472
#define O_bf1    5504
#define LDS_FLOATS 5536

// tanh(x) = 1 - 2/(1+exp(2x))
__device__ __forceinline__ float ftanh(float v) {
  float ex = __builtin_amdgcn_exp2f(v * 2.885390081777926815f);
  float r = __builtin_amdgcn_rcpf(1.0f + ex);
  return fmaf(-2.0f, r, 1.0f);
}

// DPP cross-lane: quad xor1 = 0xB1, quad xor2 = 0x4E, row_half_mirror = 0x141
__device__ __forceinline__ float qxor1(float v) {
  return __int_as_float(__builtin_amdgcn_mov_dpp(__float_as_int(v), 0xB1, 0xF, 0xF, true));
}
__device__ __forceinline__ float qxor2(float v) {
  return __int_as_float(__builtin_amdgcn_mov_dpp(__float_as_int(v), 0x4E, 0xF, 0xF, true));
}
__device__ __forceinline__ float hmir(float v) {
  return __int_as_float(__builtin_amdgcn_mov_dpp(__float_as_int(v), 0x141, 0xF, 0xF, true));
}
// sum over the 8-lane octet (pure DPP, full VALU rate)
__device__ __forceinline__ float osum(float v) {
  v += qxor1(v);
  v += qxor2(v);
  v += hmir(v);
  return v;
}
// per-lane select of one of 8 registers by p (7 cndmasks, no scratch)
__device__ __forceinline__ float osel8(float v0, float v1, float v2, float v3,
                                       float v4, float v5, float v6, float v7, int p) {
  float a = (p & 1) ? v1 : v0;
  float b = (p & 1) ? v3 : v2;
  float c = (p & 1) ? v5 : v4;
  float d = (p & 1) ? v7 : v6;
  float e0 = (p & 2) ? b : a;
  float e1 = (p & 2) ? d : c;
  return (p & 4) ? e1 : e0;
}

// 4-accumulator dot (dep depth ~6)
__device__ __forceinline__ float dot16(const float* __restrict__ W, const float* __restrict__ v) {
  float a0 = 0.f, a1 = 0.f, a2 = 0.f, a3 = 0.f;
#pragma unroll
  for (int j = 0; j < 4; ++j) {
    a0 = fmaf(W[j], v[j], a0);
    a1 = fmaf(W[j + 4], v[j + 4], a1);
    a2 = fmaf(W[j + 8], v[j + 8], a2);
    a3 = fmaf(W[j + 12], v[j + 12], a3);
  }
  return (a0 + a1) + (a2 + a3);
}
__device__ __forceinline__ float dot8(const float* __restrict__ W, const float* __restrict__ v) {
  float a0 = 0.f, a1 = 0.f;
#pragma unroll
  for (int j = 0; j < 4; ++j) {
    a0 = fmaf(W[j], v[j], a0);
    a1 = fmaf(W[j + 4], v[j + 4], a1);
  }
  return a0 + a1;
}

__global__ __launch_bounds__(256, 2) void loss_kernel(
    const float* __restrict__ x_batch, const float* __restrict__ e_batch,
    const float* __restrict__ Wf1, const float* __restrict__ bf1, const float* __restrict__ Wf2,
    const float* __restrict__ Wh1, const float* __restrict__ bh1, const float* __restrict__ Wh2,
    const float* __restrict__ WT1, const float* __restrict__ bT1, const float* __restrict__ WT2,
    const float* __restrict__ Wtau1, const float* __restrict__ btau1, const float* __restrict__ Wtau2,
    const float* __restrict__ Wpsi1, const float* __restrict__ bpsi1, const float* __restrict__ Wpsi2,
    const float* __restrict__ WP,
    float* __restrict__ out) {
  __shared__ float sW[LDS_FLOATS];
  __shared__ float wsum[4];
  const int tid = threadIdx.x;

  // ---- staging (256 threads) ----
  {
#pragma unroll
    for (int r = 0; r < 2; ++r) sW[O_WT1 + r * 256 + tid] = WT1[r * 256 + tid];
#pragma unroll
    for (int r = 0; r < 2; ++r) sW[O_Wtau1 + r * 256 + tid] = Wtau1[r * 256 + tid];
#pragma unroll
    for (int r = 0; r < 2; ++r) sW[O_Wh1 + r * 256 + tid] = Wh1[r * 256 + tid];
#pragma unroll
    for (int r = 0; r < 3; ++r) sW[O_Wpsi1 + r * 256 + tid] = Wpsi1[r * 256 + tid];
#pragma unroll
    for (int r = 0; r < 2; ++r) sW[O_Wf1 + r * 256 + tid] = Wf1[r * 256 + tid];
    sW[O_WP + tid] = WP[tid];
    // transposed: global (M,32) idx -> [k][m]
#pragma unroll
    for (int r = 0; r < 2; ++r) {
      int idx = r * 256 + tid; int j = idx >> 5, k = idx & 31;
      sW[O_WT2T + k * DNZ + j] = WT2[idx];
    }
#pragma unroll
    for (int r = 0; r < 2; ++r) {
      int idx = r * 256 + tid; int j = idx >> 5, k = idx & 31;
      sW[O_Wtau2T + k * DN + j] = Wtau2[idx];
    }
#pragma unroll
    for (int r = 0; r < 2; ++r) {
      int idx = r * 256 + tid; int j = idx >> 5, k = idx & 31;
      sW[O_Wpsi2T + k * DNZ + j] = Wpsi2[idx];
    }
#pragma unroll
    for (int r = 0; r < 2; ++r) {
      int idx = r * 256 + tid; int j = idx >> 5, k = idx & 31;
      sW[O_Wf2T + k * DN + j] = Wf2[idx];
    }
    { int o = tid >> 5, k = tid & 31; sW[O_Wh2T + k * DOUT + o] = Wh2[tid]; }
    if (tid < 32) {
      sW[O_bT1 + tid] = bT1[tid];
      sW[O_btau1 + tid] = btau1[tid];
      sW[O_bh1 + tid] = bh1[tid];
      sW[O_bpsi1 + tid] = bpsi1[tid];
      sW[O_bf1 + tid] = bf1[tid];
    }
  }
  __syncthreads();

  const int p = tid & 7;                          // lane in octet
  const int sidx = blockIdx.x * 32 + (tid >> 3);  // sample (32 per block)

  // ---- load sample (replicated across octet; cache-served) ----
  float x[DN], e[DNZ];
  {
    const float4* xp = reinterpret_cast<const float4*>(x_batch + (size_t)sidx * DN);
    const float4* ep = reinterpret_cast<const float4*>(e_batch + (size_t)sidx * DNZ);
#pragma unroll
    for (int q = 0; q < 4; ++q) {
      float4 vx = xp[q], ve = ep[q];
      x[4 * q + 0] = vx.x; x[4 * q + 1] = vx.y; x[4 * q + 2] = vx.z; x[4 * q + 3] = vx.w;
      e[4 * q + 0] = ve.x; e[4 * q + 1] = ve.y; e[4 * q + 2] = ve.z; e[4 * q + 3] = ve.w;
    }
  }

  // ---- A: z = T(x) + e ----
  float z[DNZ];
#pragma unroll
  for (int j = 0; j < DNZ; ++j) z[j] = 0.f;
#pragma unroll 2
  for (int kk = 0; kk < 4; ++kk) {
    const int k = 8 * kk + p;
    float t = ftanh(dot16(sW + O_WT1 + k * DN, x) + sW[O_bT1 + k]);
    const float* Ct = sW + O_WT2T + k * DNZ;
#pragma unroll
    for (int j = 0; j < DNZ; ++j) z[j] = fmaf(Ct[j], t, z[j]);
  }
#pragma unroll
  for (int j = 0; j < DNZ; ++j) z[j] = osum(z[j]) + e[j];

  // ---- B: xh = tau(z); x -> diff ----
  float xh[DN];
#pragma unroll
  for (int n = 0; n < DN; ++n) xh[n] = 0.f;
#pragma unroll 2
  for (int kk = 0; kk < 4; ++kk) {
    const int k = 8 * kk + p;
    float t = ftanh(dot16(sW + O_Wtau1 + k * DNZ, z) + sW[O_btau1 + k]);
    const float* Ct = sW + O_Wtau2T + k * DN;
#pragma unroll
    for (int n = 0; n < DN; ++n) xh[n] = fmaf(Ct[n], t, xh[n]);
  }
#pragma unroll
  for (int n = 0; n < DN; ++n) { xh[n] = osum(xh[n]); x[n] -= xh[n]; }

  // ---- C: yh + dth (lane-owned) ----
  float yh[DOUT];
#pragma unroll
  for (int o = 0; o < DOUT; ++o) yh[o] = 0.f;
  float dth[4];
#pragma unroll 2
  for (int kk = 0; kk < 4; ++kk) {
    const int k = 8 * kk + p;
    float t = ftanh(dot16(sW + O_Wh1 + k * DN, xh) + sW[O_bh1 + k]);
    dth[kk] = 1.f - t * t;
    const float* Ct = sW + O_Wh2T + k * DOUT;
#pragma unroll
    for (int o = 0; o < DOUT; ++o) yh[o] = fmaf(Ct[o], t, yh[o]);
  }
#pragma unroll
  for (int o = 0; o < DOUT; ++o) yh[o] = osum(yh[o]);

  // ---- D: w8 = RINV * Wh2 @ (dth ∘ (Wh1 @ diff)) ----
  float w8[DOUT];
#pragma unroll
  for (int o = 0; o < DOUT; ++o) w8[o] = 0.f;
#pragma unroll 2
  for (int kk = 0; kk < 4; ++kk) {
    const int k = 8 * kk + p;
    float g = dot16(sW + O_Wh1 + k * DN, x) * dth[kk];
    const float* Ct = sW + O_Wh2T + k * DOUT;
#pragma unroll
    for (int o = 0; o < DOUT; ++o) w8[o] = fmaf(Ct[o], g, w8[o]);
  }
#pragma unroll
  for (int o = 0; o < DOUT; ++o) w8[o] = osum(w8[o]) * RINV;

  // ---- E: u = Wh1^T @ (dth ∘ (Wh2^T @ w8)) ----
  float u[DN];
#pragma unroll
  for (int n = 0; n < DN; ++n) u[n] = 0.f;
#pragma unroll 2
  for (int kk = 0; kk < 4; ++kk) {
    const int k = 8 * kk + p;
    float g = dot8(sW + O_Wh2T + k * DOUT, w8) * dth[kk];
    const float* Wr = sW + O_Wh1 + k * DN;
#pragma unroll
    for (int n = 0; n < DN; ++n) u[n] = fmaf(Wr[n], g, u[n]);
  }
#pragma unroll
  for (int n = 0; n < DN; ++n) u[n] = osum(u[n]);

  // ---- F: sv (lane-owned n = 8nn+p), sdot; u gathered via osel8 ----
  float sv[2], usel[2];
  float sdp = 0.f;
#pragma unroll
  for (int nn = 0; nn < 2; ++nn) {
    const int n = 8 * nn + p;
    sv[nn] = ftanh(dot16(sW + O_WP + n * DN, xh));
    usel[nn] = osel8(u[8 * nn + 0], u[8 * nn + 1], u[8 * nn + 2], u[8 * nn + 3],
                     u[8 * nn + 4], u[8 * nn + 5], u[8 * nn + 6], u[8 * nn + 7], p);
    sdp = fmaf(sv[nn], usel[nn], sdp);
  }
  const float sdot = osum(sdp);

  // ---- G: Tx = T(xh) ----
  float Tx[DNZ];
#pragma unroll
  for (int j = 0; j < DNZ; ++j) Tx[j] = 0.f;
#pragma unroll 2
  for (int kk = 0; kk < 4; ++kk) {
    const int k = 8 * kk + p;
    float t = ftanh(dot16(sW + O_WT1 + k * DN, xh) + sW[O_bT1 + k]);
    const float* Ct = sW + O_WT2T + k * DNZ;
#pragma unroll
    for (int j = 0; j < DNZ; ++j) Tx[j] = fmaf(Ct[j], t, Tx[j]);
  }
#pragma unroll
  for (int j = 0; j < DNZ; ++j) Tx[j] = osum(Tx[j]);

  // ---- H: phi = psi(Tx,yh); jph = Jphi @ e ----
  float phi[DNZ], jph[DNZ];
#pragma unroll
  for (int j = 0; j < DNZ; ++j) { phi[j] = 0.f; jph[j] = 0.f; }
#pragma unroll 2
  for (int kk = 0; kk < 4; ++kk) {
    const int k = 8 * kk + p;
    const float* Wr = sW + O_Wpsi1 + k * DPSI;
    float t = ftanh(dot16(Wr, Tx) + dot8(Wr + DNZ, yh) + sW[O_bpsi1 + k]);
    float d = 1.f - t * t;
    float g = d * dot16(Wr, e);
    const float* Ct = sW + O_Wpsi2T + k * DNZ;
#pragma unroll
    for (int j = 0; j < DNZ; ++j) {
      phi[j] = fmaf(Ct[j], t, phi[j]);
      jph[j] = fmaf(Ct[j], g, jph[j]);
    }
  }
#pragma unroll
  for (int j = 0; j < DNZ; ++j) { phi[j] = osum(phi[j]); jph[j] = osum(jph[j]); }

  // ---- I: t2e = Htau@e + Jtau@jph (partial); jte = Jtau@e (reduced) ----
  float t2e[DN], jte[DN];
#pragma unroll
  for (int n = 0; n < DN; ++n) { t2e[n] = 0.f; jte[n] = 0.f; }
#pragma unroll 2
  for (int kk = 0; kk < 4; ++kk) {
    const int k = 8 * kk + p;
    const float* Wr = sW + O_Wtau1 + k * DNZ;
    float a = dot16(Wr, Tx) + sW[O_btau1 + k];
    float wp = dot16(Wr, phi);
    float v = dot16(Wr, e);
    float q = dot16(Wr, jph);
    float t = ftanh(a);
    float d = 1.f - t * t;
    float c = -2.f * t * d * wp;
    float g1 = fmaf(c, v, d * q);
    float g2 = d * v;
    const float* Ct = sW + O_Wtau2T + k * DN;
#pragma unroll
    for (int n = 0; n < DN; ++n) {
      t2e[n] = fmaf(Ct[n], g1, t2e[n]);
      jte[n] = fmaf(Ct[n], g2, jte[n]);
    }
  }
#pragma unroll
  for (int n = 0; n < DN; ++n) jte[n] = osum(jte[n]);  // t2e stays partial

  // ---- J: t2e -= Jf @ jte (accumulate into partials, then reduce) ----
#pragma unroll 2
  for (int kk = 0; kk < 4; ++kk) {
    const int k = 8 * kk + p;
    const float* Wr = sW + O_Wf1 + k * DN;
    float a = dot16(Wr, xh) + sW[O_bf1 + k];
    float gj = dot16(Wr, jte);
    float t = ftanh(a);
    float g = (1.f - t * t) * gj;
    const float* Ct = sW + O_Wf2T + k * DN;
#pragma unroll
    for (int n = 0; n < DN; ++n) t2e[n] = fmaf(-Ct[n], g, t2e[n]);
  }
#pragma unroll
  for (int n = 0; n < DN; ++n) t2e[n] = osum(t2e[n]);

  // ---- K: loss (lane-owned n = 8nn+p via osel8, octet reduce) ----
  float ss = 0.f;
#pragma unroll
  for (int nn = 0; nn < 2; ++nn) {
    float tsel = osel8(t2e[8 * nn + 0], t2e[8 * nn + 1], t2e[8 * nn + 2], t2e[8 * nn + 3],
                       t2e[8 * nn + 4], t2e[8 * nn + 5], t2e[8 * nn + 6], t2e[8 * nn + 7], p);
    float r = fmaf(sv[nn], sdot, usel[nn]) - tsel;
    ss = fmaf(r, r, ss);
  }
  ss = osum(ss);
  float loss = sqrtf(ss);  // same on all 8 octet lanes

  // wave reduce across octets: offsets >=8 pair distinct octets -> each
  // octet's loss counted exactly once; wave sum = 8 sample losses.
#pragma unroll
  for (int off = 8; off < 64; off <<= 1) loss += __shfl_xor(loss, off);

  // block reduce: 4 waves (32 samples) -> one atomic per block
  if ((tid & 63) == 0) wsum[tid >> 6] = loss;
  __syncthreads();
  if (tid == 0)
    atomicAdd(out, (wsum[0] + wsum[1] + wsum[2] + wsum[3]) * (1.0f / (float)DB));
}

extern "C" void kernel_launch(void* const* d_in, const int* in_sizes, int n_in,
                              void* d_out, int out_size, void* d_ws, size_t ws_size,
                              hipStream_t stream) {
  const float* x_batch = (const float*)d_in[0];
  const float* e_batch = (const float*)d_in[1];
  const float* Wf1 = (const float*)d_in[2];
  const float* bf1 = (const float*)d_in[3];
  const float* Wf2 = (const float*)d_in[4];
  const float* Wh1 = (const float*)d_in[5];
  const float* bh1 = (const float*)d_in[6];
  const float* Wh2 = (const float*)d_in[7];
  const float* WT1 = (const float*)d_in[8];
  const float* bT1 = (const float*)d_in[9];
  const float* WT2 = (const float*)d_in[10];
  const float* Wtau1 = (const float*)d_in[11];
  const float* btau1 = (const float*)d_in[12];
  const float* Wtau2 = (const float*)d_in[13];
  const float* Wpsi1 = (const float*)d_in[14];
  const float* bpsi1 = (const float*)d_in[15];
  const float* Wpsi2 = (const float*)d_in[16];
  const float* WP = (const float*)d_in[17];

  hipMemsetAsync(d_out, 0, sizeof(float), stream);
  loss_kernel<<<DB / 32, 256, 0, stream>>>(
      x_batch, e_batch, Wf1, bf1, Wf2, Wh1, bh1, Wh2, WT1, bT1, WT2,
      Wtau1, btau1, Wtau2, Wpsi1, bpsi1, Wpsi2, WP, (float*)d_out);
}

// Round 8
// 27.393 us; speedup vs baseline: 1.8619x; 1.0012x over previous
//
#include <hip/hip_runtime.h>
#include <hip/hip_fp16.h>
#include <math.h>

#define DN 16
#define DNZ 16
#define DOUT 8
#define DH 32
#define DB 16384
#define RINV 10.0f
#define DPSI 24  // NZ+OUT

// ---- LDS layout in HALVES; second-layer weights TRANSPOSED [k][m] ----
// all offsets multiples of 8 halves (16B) so rows are b128-aligned
#define O_WT1    0      // 32x16
#define O_WT2T   512    // 32x16
#define O_Wtau1  1024   // 32x16
#define O_Wtau2T 1536   // 32x16
#define O_Wh1    2048   // 32x16
#define O_Wh2T   2560   // 32x8
#define O_Wpsi1  2816   // 32x24
#define O_Wpsi2T 3584   // 32x16
#define O_Wf1    4096   // 32x16
#define O_Wf2T   4608   // 32x16
#define O_WP     5120   // 16x16
#define LDS_HALVES 5376
// biases kept fp32
#define B_T1   0
#define B_tau1 32
#define B_h1   64
#define B_psi1 96
#define B_f1   128

// tanh(x) = 1 - 2/(1+exp(2x))
__device__ __forceinline__ float ftanh(float v) {
  float ex = __builtin_amdgcn_exp2f(v * 2.885390081777926815f);
  float r = __builtin_amdgcn_rcpf(1.0f + ex);
  return fmaf(-2.0f, r, 1.0f);
}

// DPP cross-lane: quad xor1 = 0xB1, quad xor2 = 0x4E, row_half_mirror = 0x141
__device__ __forceinline__ float qxor1(float v) {
  return __int_as_float(__builtin_amdgcn_mov_dpp(__float_as_int(v), 0xB1, 0xF, 0xF, true));
}
__device__ __forceinline__ float qxor2(float v) {
  return __int_as_float(__builtin_amdgcn_mov_dpp(__float_as_int(v), 0x4E, 0xF, 0xF, true));
}
__device__ __forceinline__ float hmir(float v) {
  return __int_as_float(__builtin_amdgcn_mov_dpp(__float_as_int(v), 0x141, 0xF, 0xF, true));
}
// sum over the 8-lane octet (pure DPP, full VALU rate)
__device__ __forceinline__ float osum(float v) {
  v += qxor1(v);
  v += qxor2(v);
  v += hmir(v);
  return v;
}
// per-lane select of one of 8 registers by p (7 cndmasks, no scratch)
__device__ __forceinline__ float osel8(float v0, float v1, float v2, float v3,
                                       float v4, float v5, float v6, float v7, int p) {
  float a = (p & 1) ? v1 : v0;
  float b = (p & 1) ? v3 : v2;
  float c = (p & 1) ? v5 : v4;
  float d = (p & 1) ? v7 : v6;
  float e0 = (p & 2) ? b : a;
  float e1 = (p & 2) ? d : c;
  return (p & 4) ? e1 : e0;
}

// unpack a 16-half LDS row into fp32 regs (2 x ds_read_b128 + cvts/fma_mix)
__device__ __forceinline__ void row16h(const __half* __restrict__ W, float* __restrict__ wr) {
  const __half2* w2 = reinterpret_cast<const __half2*>(W);
#pragma unroll
  for (int j = 0; j < 8; ++j) {
    __half2 h = w2[j];
    wr[2 * j] = __low2float(h);
    wr[2 * j + 1] = __high2float(h);
  }
}
__device__ __forceinline__ void row8h(const __half* __restrict__ W, float* __restrict__ wr) {
  const __half2* w2 = reinterpret_cast<const __half2*>(W);
#pragma unroll
  for (int j = 0; j < 4; ++j) {
    __half2 h = w2[j];
    wr[2 * j] = __low2float(h);
    wr[2 * j + 1] = __high2float(h);
  }
}
__device__ __forceinline__ void row24h(const __half* __restrict__ W, float* __restrict__ wr) {
  const __half2* w2 = reinterpret_cast<const __half2*>(W);
#pragma unroll
  for (int j = 0; j < 12; ++j) {
    __half2 h = w2[j];
    wr[2 * j] = __low2float(h);
    wr[2 * j + 1] = __high2float(h);
  }
}

// register-resident dots, 4/2 accumulators
__device__ __forceinline__ float dot16r(const float* __restrict__ w, const float* __restrict__ v) {
  float a0 = 0.f, a1 = 0.f, a2 = 0.f, a3 = 0.f;
#pragma unroll
  for (int j = 0; j < 4; ++j) {
    a0 = fmaf(w[j], v[j], a0);
    a1 = fmaf(w[j + 4], v[j + 4], a1);
    a2 = fmaf(w[j + 8], v[j + 8], a2);
    a3 = fmaf(w[j + 12], v[j + 12], a3);
  }
  return (a0 + a1) + (a2 + a3);
}
__device__ __forceinline__ float dot8r(const float* __restrict__ w, const float* __restrict__ v) {
  float a0 = 0.f, a1 = 0.f;
#pragma unroll
  for (int j = 0; j < 4; ++j) {
    a0 = fmaf(w[j], v[j], a0);
    a1 = fmaf(w[j + 4], v[j + 4], a1);
  }
  return a0 + a1;
}

__global__ __launch_bounds__(256, 2) void loss_kernel(
    const float* __restrict__ x_batch, const float* __restrict__ e_batch,
    const float* __restrict__ Wf1, const float* __restrict__ bf1, const float* __restrict__ Wf2,
    const float* __restrict__ Wh1, const float* __restrict__ bh1, const float* __restrict__ Wh2,
    const float* __restrict__ WT1, const float* __restrict__ bT1, const float* __restrict__ WT2,
    const float* __restrict__ Wtau1, const float* __restrict__ btau1, const float* __restrict__ Wtau2,
    const float* __restrict__ Wpsi1, const float* __restrict__ bpsi1, const float* __restrict__ Wpsi2,
    const float* __restrict__ WP,
    float* __restrict__ out) {
  __shared__ __half sH[LDS_HALVES];
  __shared__ float sB[160];
  __shared__ float wsum[4];
  const int tid = threadIdx.x;

  // ---- staging (256 threads), fp32 -> fp16 ----
  {
#pragma unroll
    for (int r = 0; r < 2; ++r) sH[O_WT1 + r * 256 + tid] = __float2half(WT1[r * 256 + tid]);
#pragma unroll
    for (int r = 0; r < 2; ++r) sH[O_Wtau1 + r * 256 + tid] = __float2half(Wtau1[r * 256 + tid]);
#pragma unroll
    for (int r = 0; r < 2; ++r) sH[O_Wh1 + r * 256 + tid] = __float2half(Wh1[r * 256 + tid]);
#pragma unroll
    for (int r = 0; r < 3; ++r) sH[O_Wpsi1 + r * 256 + tid] = __float2half(Wpsi1[r * 256 + tid]);
#pragma unroll
    for (int r = 0; r < 2; ++r) sH[O_Wf1 + r * 256 + tid] = __float2half(Wf1[r * 256 + tid]);
    sH[O_WP + tid] = __float2half(WP[tid]);
    // transposed: global (M,32) idx -> [k][m]
#pragma unroll
    for (int r = 0; r < 2; ++r) {
      int idx = r * 256 + tid; int j = idx >> 5, k = idx & 31;
      sH[O_WT2T + k * DNZ + j] = __float2half(WT2[idx]);
    }
#pragma unroll
    for (int r = 0; r < 2; ++r) {
      int idx = r * 256 + tid; int j = idx >> 5, k = idx & 31;
      sH[O_Wtau2T + k * DN + j] = __float2half(Wtau2[idx]);
    }
#pragma unroll
    for (int r = 0; r < 2; ++r) {
      int idx = r * 256 + tid; int j = idx >> 5, k = idx & 31;
      sH[O_Wpsi2T + k * DNZ + j] = __float2half(Wpsi2[idx]);
    }
#pragma unroll
    for (int r = 0; r < 2; ++r) {
      int idx = r * 256 + tid; int j = idx >> 5, k = idx & 31;
      sH[O_Wf2T + k * DN + j] = __float2half(Wf2[idx]);
    }
    { int o = tid >> 5, k = tid & 31; sH[O_Wh2T + k * DOUT + o] = __float2half(Wh2[tid]); }
    if (tid < 32) {
      sB[B_T1 + tid] = bT1[tid];
      sB[B_tau1 + tid] = btau1[tid];
      sB[B_h1 + tid] = bh1[tid];
      sB[B_psi1 + tid] = bpsi1[tid];
      sB[B_f1 + tid] = bf1[tid];
    }
  }
  __syncthreads();

  const int p = tid & 7;                          // lane in octet
  const int sidx = blockIdx.x * 32 + (tid >> 3);  // sample (32 per block)

  // ---- load sample (replicated across octet; cache-served) ----
  float x[DN], e[DNZ];
  {
    const float4* xp = reinterpret_cast<const float4*>(x_batch + (size_t)sidx * DN);
    const float4* ep = reinterpret_cast<const float4*>(e_batch + (size_t)sidx * DNZ);
#pragma unroll
    for (int q = 0; q < 4; ++q) {
      float4 vx = xp[q], ve = ep[q];
      x[4 * q + 0] = vx.x; x[4 * q + 1] = vx.y; x[4 * q + 2] = vx.z; x[4 * q + 3] = vx.w;
      e[4 * q + 0] = ve.x; e[4 * q + 1] = ve.y; e[4 * q + 2] = ve.z; e[4 * q + 3] = ve.w;
    }
  }

  // ---- A: z = T(x) + e ----
  float z[DNZ];
#pragma unroll
  for (int j = 0; j < DNZ; ++j) z[j] = 0.f;
#pragma unroll 2
  for (int kk = 0; kk < 4; ++kk) {
    const int k = 8 * kk + p;
    float wr[16]; row16h(sH + O_WT1 + k * DN, wr);
    float t = ftanh(dot16r(wr, x) + sB[B_T1 + k]);
    float cw[16]; row16h(sH + O_WT2T + k * DNZ, cw);
#pragma unroll
    for (int j = 0; j < DNZ; ++j) z[j] = fmaf(cw[j], t, z[j]);
  }
#pragma unroll
  for (int j = 0; j < DNZ; ++j) z[j] = osum(z[j]) + e[j];

  // ---- B: xh = tau(z); x -> diff ----
  float xh[DN];
#pragma unroll
  for (int n = 0; n < DN; ++n) xh[n] = 0.f;
#pragma unroll 2
  for (int kk = 0; kk < 4; ++kk) {
    const int k = 8 * kk + p;
    float wr[16]; row16h(sH + O_Wtau1 + k * DNZ, wr);
    float t = ftanh(dot16r(wr, z) + sB[B_tau1 + k]);
    float cw[16]; row16h(sH + O_Wtau2T + k * DN, cw);
#pragma unroll
    for (int n = 0; n < DN; ++n) xh[n] = fmaf(cw[n], t, xh[n]);
  }
#pragma unroll
  for (int n = 0; n < DN; ++n) { xh[n] = osum(xh[n]); x[n] -= xh[n]; }

  // ---- C+D fused: yh, dth, w8 (one pass over Wh1/Wh2T) ----
  float yh[DOUT], w8[DOUT];
#pragma unroll
  for (int o = 0; o < DOUT; ++o) { yh[o] = 0.f; w8[o] = 0.f; }
  float dth[4];
#pragma unroll 2
  for (int kk = 0; kk < 4; ++kk) {
    const int k = 8 * kk + p;
    float wr[16]; row16h(sH + O_Wh1 + k * DN, wr);
    float t = ftanh(dot16r(wr, xh) + sB[B_h1 + k]);
    float d = 1.f - t * t;
    dth[kk] = d;
    float g = dot16r(wr, x) * d;  // x = diff
    float cw[8]; row8h(sH + O_Wh2T + k * DOUT, cw);
#pragma unroll
    for (int o = 0; o < DOUT; ++o) {
      yh[o] = fmaf(cw[o], t, yh[o]);
      w8[o] = fmaf(cw[o], g, w8[o]);
    }
  }
#pragma unroll
  for (int o = 0; o < DOUT; ++o) { yh[o] = osum(yh[o]); w8[o] = osum(w8[o]) * RINV; }

  // ---- E: u = Wh1^T @ (dth ∘ (Wh2^T @ w8)) ----
  float u[DN];
#pragma unroll
  for (int n = 0; n < DN; ++n) u[n] = 0.f;
#pragma unroll 2
  for (int kk = 0; kk < 4; ++kk) {
    const int k = 8 * kk + p;
    float cw[8]; row8h(sH + O_Wh2T + k * DOUT, cw);
    float g = dot8r(cw, w8) * dth[kk];
    float wr[16]; row16h(sH + O_Wh1 + k * DN, wr);
#pragma unroll
    for (int n = 0; n < DN; ++n) u[n] = fmaf(wr[n], g, u[n]);
  }
#pragma unroll
  for (int n = 0; n < DN; ++n) u[n] = osum(u[n]);

  // ---- F: sv (lane-owned n = 8nn+p), sdot; u gathered via osel8 ----
  float sv[2], usel[2];
  float sdp = 0.f;
#pragma unroll
  for (int nn = 0; nn < 2; ++nn) {
    const int n = 8 * nn + p;
    float wr[16]; row16h(sH + O_WP + n * DN, wr);
    sv[nn] = ftanh(dot16r(wr, xh));
    usel[nn] = osel8(u[8 * nn + 0], u[8 * nn + 1], u[8 * nn + 2], u[8 * nn + 3],
                     u[8 * nn + 4], u[8 * nn + 5], u[8 * nn + 6], u[8 * nn + 7], p);
    sdp = fmaf(sv[nn], usel[nn], sdp);
  }
  const float sdot = osum(sdp);

  // ---- G: Tx = T(xh) ----
  float Tx[DNZ];
#pragma unroll
  for (int j = 0; j < DNZ; ++j) Tx[j] = 0.f;
#pragma unroll 2
  for (int kk = 0; kk < 4; ++kk) {
    const int k = 8 * kk + p;
    float wr[16]; row16h(sH + O_WT1 + k * DN, wr);
    float t = ftanh(dot16r(wr, xh) + sB[B_T1 + k]);
    float cw[16]; row16h(sH + O_WT2T + k * DNZ, cw);
#pragma unroll
    for (int j = 0; j < DNZ; ++j) Tx[j] = fmaf(cw[j], t, Tx[j]);
  }
#pragma unroll
  for (int j = 0; j < DNZ; ++j) Tx[j] = osum(Tx[j]);

  // ---- H: phi = psi(Tx,yh); jph = Jphi @ e ----
  float phi[DNZ], jph[DNZ];
#pragma unroll
  for (int j = 0; j < DNZ; ++j) { phi[j] = 0.f; jph[j] = 0.f; }
#pragma unroll 2
  for (int kk = 0; kk < 4; ++kk) {
    const int k = 8 * kk + p;
    float wr[24]; row24h(sH + O_Wpsi1 + k * DPSI, wr);
    float t = ftanh(dot16r(wr, Tx) + dot8r(wr + DNZ, yh) + sB[B_psi1 + k]);
    float d = 1.f - t * t;
    float g = d * dot16r(wr, e);
    float cw[16]; row16h(sH + O_Wpsi2T + k * DNZ, cw);
#pragma unroll
    for (int j = 0; j < DNZ; ++j) {
      phi[j] = fmaf(cw[j], t, phi[j]);
      jph[j] = fmaf(cw[j], g, jph[j]);
    }
  }
#pragma unroll
  for (int j = 0; j < DNZ; ++j) { phi[j] = osum(phi[j]); jph[j] = osum(jph[j]); }

  // ---- I: t2e = Htau@e + Jtau@jph (partial); jte = Jtau@e (reduced) ----
  float t2e[DN], jte[DN];
#pragma unroll
  for (int n = 0; n < DN; ++n) { t2e[n] = 0.f; jte[n] = 0.f; }
#pragma unroll 2
  for (int kk = 0; kk < 4; ++kk) {
    const int k = 8 * kk + p;
    float wr[16]; row16h(sH + O_Wtau1 + k * DNZ, wr);
    float a = dot16r(wr, Tx) + sB[B_tau1 + k];
    float wp = dot16r(wr, phi);
    float v = dot16r(wr, e);
    float q = dot16r(wr, jph);
    float t = ftanh(a);
    float d = 1.f - t * t;
    float c = -2.f * t * d * wp;
    float g1 = fmaf(c, v, d * q);
    float g2 = d * v;
    float cw[16]; row16h(sH + O_Wtau2T + k * DN, cw);
#pragma unroll
    for (int n = 0; n < DN; ++n) {
      t2e[n] = fmaf(cw[n], g1, t2e[n]);
      jte[n] = fmaf(cw[n], g2, jte[n]);
    }
  }
#pragma unroll
  for (int n = 0; n < DN; ++n) jte[n] = osum(jte[n]);  // t2e stays partial

  // ---- J: t2e -= Jf @ jte (accumulate into partials, then reduce) ----
#pragma unroll 2
  for (int kk = 0; kk < 4; ++kk) {
    const int k = 8 * kk + p;
    float wr[16]; row16h(sH + O_Wf1 + k * DN, wr);
    float a = dot16r(wr, xh) + sB[B_f1 + k];
    float gj = dot16r(wr, jte);
    float t = ftanh(a);
    float g = (1.f - t * t) * gj;
    float cw[16]; row16h(sH + O_Wf2T + k * DN, cw);
#pragma unroll
    for (int n = 0; n < DN; ++n) t2e[n] = fmaf(-cw[n], g, t2e[n]);
  }
#pragma unroll
  for (int n = 0; n < DN; ++n) t2e[n] = osum(t2e[n]);

  // ---- K: loss (lane-owned n = 8nn+p via osel8, octet reduce) ----
  float ss = 0.f;
#pragma unroll
  for (int nn = 0; nn < 2; ++nn) {
    float tsel = osel8(t2e[8 * nn + 0], t2e[8 * nn + 1], t2e[8 * nn + 2], t2e[8 * nn + 3],
                       t2e[8 * nn + 4], t2e[8 * nn + 5], t2e[8 * nn + 6], t2e[8 * nn + 7], p);
    float r = fmaf(sv[nn], sdot, usel[nn]) - tsel;
    ss = fmaf(r, r, ss);
  }
  ss = osum(ss);
  float loss = sqrtf(ss);  // same on all 8 octet lanes

  // wave reduce across octets: offsets >=8 pair distinct octets -> each
  // octet's loss counted exactly once; wave sum = 8 sample losses.
#pragma unroll
  for (int off = 8; off < 64; off <<= 1) loss += __shfl_xor(loss, off);

  // block reduce: 4 waves (32 samples) -> one atomic per block
  if ((tid & 63) == 0) wsum[tid >> 6] = loss;
  __syncthreads();
  if (tid == 0)
    atomicAdd(out, (wsum[0] + wsum[1] + wsum[2] + wsum[3]) * (1.0f / (float)DB));
}

extern "C" void kernel_launch(void* const* d_in, const int* in_sizes, int n_in,
                              void* d_out, int out_size, void* d_ws, size_t ws_size,
                              hipStream_t stream) {
  const float* x_batch = (const float*)d_in[0];
  const float* e_batch = (const float*)d_in[1];
  const float* Wf1 = (const float*)d_in[2];
  const float* bf1 = (const float*)d_in[3];
  const float* Wf2 = (const float*)d_in[4];
  const float* Wh1 = (const float*)d_in[5];
  const float* bh1 = (const float*)d_in[6];
  const float* Wh2 = (const float*)d_in[7];
  const float* WT1 = (const float*)d_in[8];
  const float* bT1 = (const float*)d_in[9];
  const float* WT2 = (const float*)d_in[10];
  const float* Wtau1 = (const float*)d_in[11];
  const float* btau1 = (const float*)d_in[12];
  const float* Wtau2 = (const float*)d_in[13];
  const float* Wpsi1 = (const float*)d_in[14];
  const float* bpsi1 = (const float*)d_in[15];
  const float* Wpsi2 = (const float*)d_in[16];
  const float* WP = (const float*)d_in[17];

  hipMemsetAsync(d_out, 0, sizeof(float), stream);
  loss_kernel<<<DB / 32, 256, 0, stream>>>(
      x_batch, e_batch, Wf1, bf1, Wf2, Wh1, bh1, Wh2, WT1, bT1, WT2,
      Wtau1, btau1, Wtau2, Wpsi1, bpsi1, Wpsi2, WP, (float*)d_out);
}

// Round 9
// 21.914 us; speedup vs baseline: 2.3274x; 1.2500x over previous
//
#include <hip/hip_runtime.h>
#include <hip/hip_fp16.h>
#include <math.h>

#define DN 16
#define DNZ 16
#define DOUT 8
#define DH 32
#define DB 16384
#define RINV 10.0f
#define DPSI 24  // NZ+OUT
#define NBLK (DB / 32)  // 512 blocks

// ---- LDS layout in HALVES; second-layer weights TRANSPOSED [k][m] ----
#define O_WT1    0      // 32x16
#define O_WT2T   512    // 32x16
#define O_Wtau1  1024   // 32x16
#define O_Wtau2T 1536   // 32x16
#define O_Wh1    2048   // 32x16
#define O_Wh2T   2560   // 32x8
#define O_Wpsi1  2816   // 32x24
#define O_Wpsi2T 3584   // 32x16
#define O_Wf1    4096   // 32x16
#define O_Wf2T   4608   // 32x16
#define O_WP     5120   // 16x16
#define LDS_HALVES 5376
// biases kept fp32
#define B_T1   0
#define B_tau1 32
#define B_h1   64
#define B_psi1 96
#define B_f1   128

// tanh(x) = 1 - 2/(1+exp(2x))
__device__ __forceinline__ float ftanh(float v) {
  float ex = __builtin_amdgcn_exp2f(v * 2.885390081777926815f);
  float r = __builtin_amdgcn_rcpf(1.0f + ex);
  return fmaf(-2.0f, r, 1.0f);
}

// DPP cross-lane: quad xor1 = 0xB1, quad xor2 = 0x4E, row_half_mirror = 0x141
__device__ __forceinline__ float qxor1(float v) {
  return __int_as_float(__builtin_amdgcn_mov_dpp(__float_as_int(v), 0xB1, 0xF, 0xF, true));
}
__device__ __forceinline__ float qxor2(float v) {
  return __int_as_float(__builtin_amdgcn_mov_dpp(__float_as_int(v), 0x4E, 0xF, 0xF, true));
}
__device__ __forceinline__ float hmir(float v) {
  return __int_as_float(__builtin_amdgcn_mov_dpp(__float_as_int(v), 0x141, 0xF, 0xF, true));
}
// sum over the 8-lane octet (pure DPP, full VALU rate)
__device__ __forceinline__ float osum(float v) {
  v += qxor1(v);
  v += qxor2(v);
  v += hmir(v);
  return v;
}
// per-lane select of one of 8 registers by p (7 cndmasks, no scratch)
__device__ __forceinline__ float osel8(float v0, float v1, float v2, float v3,
                                       float v4, float v5, float v6, float v7, int p) {
  float a = (p & 1) ? v1 : v0;
  float b = (p & 1) ? v3 : v2;
  float c = (p & 1) ? v5 : v4;
  float d = (p & 1) ? v7 : v6;
  float e0 = (p & 2) ? b : a;
  float e1 = (p & 2) ? d : c;
  return (p & 4) ? e1 : e0;
}

// unpack a 16-half LDS row into fp32 regs (2 x ds_read_b128 + cvts)
__device__ __forceinline__ void row16h(const __half* __restrict__ W, float* __restrict__ wr) {
  const __half2* w2 = reinterpret_cast<const __half2*>(W);
#pragma unroll
  for (int j = 0; j < 8; ++j) {
    __half2 h = w2[j];
    wr[2 * j] = __low2float(h);
    wr[2 * j + 1] = __high2float(h);
  }
}
__device__ __forceinline__ void row8h(const __half* __restrict__ W, float* __restrict__ wr) {
  const __half2* w2 = reinterpret_cast<const __half2*>(W);
#pragma unroll
  for (int j = 0; j < 4; ++j) {
    __half2 h = w2[j];
    wr[2 * j] = __low2float(h);
    wr[2 * j + 1] = __high2float(h);
  }
}
__device__ __forceinline__ void row24h(const __half* __restrict__ W, float* __restrict__ wr) {
  const __half2* w2 = reinterpret_cast<const __half2*>(W);
#pragma unroll
  for (int j = 0; j < 12; ++j) {
    __half2 h = w2[j];
    wr[2 * j] = __low2float(h);
    wr[2 * j + 1] = __high2float(h);
  }
}

// register-resident dots, 4/2 accumulators
__device__ __forceinline__ float dot16r(const float* __restrict__ w, const float* __restrict__ v) {
  float a0 = 0.f, a1 = 0.f, a2 = 0.f, a3 = 0.f;
#pragma unroll
  for (int j = 0; j < 4; ++j) {
    a0 = fmaf(w[j], v[j], a0);
    a1 = fmaf(w[j + 4], v[j + 4], a1);
    a2 = fmaf(w[j + 8], v[j + 8], a2);
    a3 = fmaf(w[j + 12], v[j + 12], a3);
  }
  return (a0 + a1) + (a2 + a3);
}
__device__ __forceinline__ float dot8r(const float* __restrict__ w, const float* __restrict__ v) {
  float a0 = 0.f, a1 = 0.f;
#pragma unroll
  for (int j = 0; j < 4; ++j) {
    a0 = fmaf(w[j], v[j], a0);
    a1 = fmaf(w[j + 4], v[j + 4], a1);
  }
  return a0 + a1;
}

__global__ __launch_bounds__(256, 2) void loss_kernel(
    const float* __restrict__ x_batch, const float* __restrict__ e_batch,
    const float* __restrict__ Wf1, const float* __restrict__ bf1, const float* __restrict__ Wf2,
    const float* __restrict__ Wh1, const float* __restrict__ bh1, const float* __restrict__ Wh2,
    const float* __restrict__ WT1, const float* __restrict__ bT1, const float* __restrict__ WT2,
    const float* __restrict__ Wtau1, const float* __restrict__ btau1, const float* __restrict__ Wtau2,
    const float* __restrict__ Wpsi1, const float* __restrict__ bpsi1, const float* __restrict__ Wpsi2,
    const float* __restrict__ WP,
    float* __restrict__ part) {
  __shared__ __half sH[LDS_HALVES];
  __shared__ float sB[160];
  __shared__ float wsum[4];
  const int tid = threadIdx.x;

  // ---- staging (256 threads), fp32 -> fp16 ----
  {
#pragma unroll
    for (int r = 0; r < 2; ++r) sH[O_WT1 + r * 256 + tid] = __float2half(WT1[r * 256 + tid]);
#pragma unroll
    for (int r = 0; r < 2; ++r) sH[O_Wtau1 + r * 256 + tid] = __float2half(Wtau1[r * 256 + tid]);
#pragma unroll
    for (int r = 0; r < 2; ++r) sH[O_Wh1 + r * 256 + tid] = __float2half(Wh1[r * 256 + tid]);
#pragma unroll
    for (int r = 0; r < 3; ++r) sH[O_Wpsi1 + r * 256 + tid] = __float2half(Wpsi1[r * 256 + tid]);
#pragma unroll
    for (int r = 0; r < 2; ++r) sH[O_Wf1 + r * 256 + tid] = __float2half(Wf1[r * 256 + tid]);
    sH[O_WP + tid] = __float2half(WP[tid]);
    // transposed: global (M,32) idx -> [k][m]
#pragma unroll
    for (int r = 0; r < 2; ++r) {
      int idx = r * 256 + tid; int j = idx >> 5, k = idx & 31;
      sH[O_WT2T + k * DNZ + j] = __float2half(WT2[idx]);
    }
#pragma unroll
    for (int r = 0; r < 2; ++r) {
      int idx = r * 256 + tid; int j = idx >> 5, k = idx & 31;
      sH[O_Wtau2T + k * DN + j] = __float2half(Wtau2[idx]);
    }
#pragma unroll
    for (int r = 0; r < 2; ++r) {
      int idx = r * 256 + tid; int j = idx >> 5, k = idx & 31;
      sH[O_Wpsi2T + k * DNZ + j] = __float2half(Wpsi2[idx]);
    }
#pragma unroll
    for (int r = 0; r < 2; ++r) {
      int idx = r * 256 + tid; int j = idx >> 5, k = idx & 31;
      sH[O_Wf2T + k * DN + j] = __float2half(Wf2[idx]);
    }
    { int o = tid >> 5, k = tid & 31; sH[O_Wh2T + k * DOUT + o] = __float2half(Wh2[tid]); }
    if (tid < 32) {
      sB[B_T1 + tid] = bT1[tid];
      sB[B_tau1 + tid] = btau1[tid];
      sB[B_h1 + tid] = bh1[tid];
      sB[B_psi1 + tid] = bpsi1[tid];
      sB[B_f1 + tid] = bf1[tid];
    }
  }
  __syncthreads();

  const int p = tid & 7;                          // lane in octet
  const int sidx = blockIdx.x * 32 + (tid >> 3);  // sample (32 per block)

  // ---- load sample (replicated across octet; cache-served) ----
  float x[DN], e[DNZ];
  {
    const float4* xp = reinterpret_cast<const float4*>(x_batch + (size_t)sidx * DN);
    const float4* ep = reinterpret_cast<const float4*>(e_batch + (size_t)sidx * DNZ);
#pragma unroll
    for (int q = 0; q < 4; ++q) {
      float4 vx = xp[q], ve = ep[q];
      x[4 * q + 0] = vx.x; x[4 * q + 1] = vx.y; x[4 * q + 2] = vx.z; x[4 * q + 3] = vx.w;
      e[4 * q + 0] = ve.x; e[4 * q + 1] = ve.y; e[4 * q + 2] = ve.z; e[4 * q + 3] = ve.w;
    }
  }

  // ---- A: z = T(x) + e ----
  float z[DNZ];
#pragma unroll
  for (int j = 0; j < DNZ; ++j) z[j] = 0.f;
#pragma unroll 2
  for (int kk = 0; kk < 4; ++kk) {
    const int k = 8 * kk + p;
    float wr[16]; row16h(sH + O_WT1 + k * DN, wr);
    float t = ftanh(dot16r(wr, x) + sB[B_T1 + k]);
    float cw[16]; row16h(sH + O_WT2T + k * DNZ, cw);
#pragma unroll
    for (int j = 0; j < DNZ; ++j) z[j] = fmaf(cw[j], t, z[j]);
  }
#pragma unroll
  for (int j = 0; j < DNZ; ++j) z[j] = osum(z[j]) + e[j];

  // ---- B: xh = tau(z); x -> diff ----
  float xh[DN];
#pragma unroll
  for (int n = 0; n < DN; ++n) xh[n] = 0.f;
#pragma unroll 2
  for (int kk = 0; kk < 4; ++kk) {
    const int k = 8 * kk + p;
    float wr[16]; row16h(sH + O_Wtau1 + k * DNZ, wr);
    float t = ftanh(dot16r(wr, z) + sB[B_tau1 + k]);
    float cw[16]; row16h(sH + O_Wtau2T + k * DN, cw);
#pragma unroll
    for (int n = 0; n < DN; ++n) xh[n] = fmaf(cw[n], t, xh[n]);
  }
#pragma unroll
  for (int n = 0; n < DN; ++n) { xh[n] = osum(xh[n]); x[n] -= xh[n]; }

  // ---- C+D fused: yh, dth, w8 (one pass over Wh1/Wh2T) ----
  float yh[DOUT], w8[DOUT];
#pragma unroll
  for (int o = 0; o < DOUT; ++o) { yh[o] = 0.f; w8[o] = 0.f; }
  float dth[4];
#pragma unroll 2
  for (int kk = 0; kk < 4; ++kk) {
    const int k = 8 * kk + p;
    float wr[16]; row16h(sH + O_Wh1 + k * DN, wr);
    float t = ftanh(dot16r(wr, xh) + sB[B_h1 + k]);
    float d = 1.f - t * t;
    dth[kk] = d;
    float g = dot16r(wr, x) * d;  // x = diff
    float cw[8]; row8h(sH + O_Wh2T + k * DOUT, cw);
#pragma unroll
    for (int o = 0; o < DOUT; ++o) {
      yh[o] = fmaf(cw[o], t, yh[o]);
      w8[o] = fmaf(cw[o], g, w8[o]);
    }
  }
#pragma unroll
  for (int o = 0; o < DOUT; ++o) { yh[o] = osum(yh[o]); w8[o] = osum(w8[o]) * RINV; }

  // ---- E: u = Wh1^T @ (dth ∘ (Wh2^T @ w8)) ----
  float u[DN];
#pragma unroll
  for (int n = 0; n < DN; ++n) u[n] = 0.f;
#pragma unroll 2
  for (int kk = 0; kk < 4; ++kk) {
    const int k = 8 * kk + p;
    float cw[8]; row8h(sH + O_Wh2T + k * DOUT, cw);
    float g = dot8r(cw, w8) * dth[kk];
    float wr[16]; row16h(sH + O_Wh1 + k * DN, wr);
#pragma unroll
    for (int n = 0; n < DN; ++n) u[n] = fmaf(wr[n], g, u[n]);
  }
#pragma unroll
  for (int n = 0; n < DN; ++n) u[n] = osum(u[n]);

  // ---- F: sv (lane-owned n = 8nn+p), sdot; u gathered via osel8 ----
  float sv[2], usel[2];
  float sdp = 0.f;
#pragma unroll
  for (int nn = 0; nn < 2; ++nn) {
    const int n = 8 * nn + p;
    float wr[16]; row16h(sH + O_WP + n * DN, wr);
    sv[nn] = ftanh(dot16r(wr, xh));
    usel[nn] = osel8(u[8 * nn + 0], u[8 * nn + 1], u[8 * nn + 2], u[8 * nn + 3],
                     u[8 * nn + 4], u[8 * nn + 5], u[8 * nn + 6], u[8 * nn + 7], p);
    sdp = fmaf(sv[nn], usel[nn], sdp);
  }
  const float sdot = osum(sdp);

  // ---- G: Tx = T(xh) ----
  float Tx[DNZ];
#pragma unroll
  for (int j = 0; j < DNZ; ++j) Tx[j] = 0.f;
#pragma unroll 2
  for (int kk = 0; kk < 4; ++kk) {
    const int k = 8 * kk + p;
    float wr[16]; row16h(sH + O_WT1 + k * DN, wr);
    float t = ftanh(dot16r(wr, xh) + sB[B_T1 + k]);
    float cw[16]; row16h(sH + O_WT2T + k * DNZ, cw);
#pragma unroll
    for (int j = 0; j < DNZ; ++j) Tx[j] = fmaf(cw[j], t, Tx[j]);
  }
#pragma unroll
  for (int j = 0; j < DNZ; ++j) Tx[j] = osum(Tx[j]);

  // ---- H: phi = psi(Tx,yh); jph = Jphi @ e ----
  float phi[DNZ], jph[DNZ];
#pragma unroll
  for (int j = 0; j < DNZ; ++j) { phi[j] = 0.f; jph[j] = 0.f; }
#pragma unroll 2
  for (int kk = 0; kk < 4; ++kk) {
    const int k = 8 * kk + p;
    float wr[24]; row24h(sH + O_Wpsi1 + k * DPSI, wr);
    float t = ftanh(dot16r(wr, Tx) + dot8r(wr + DNZ, yh) + sB[B_psi1 + k]);
    float d = 1.f - t * t;
    float g = d * dot16r(wr, e);
    float cw[16]; row16h(sH + O_Wpsi2T + k * DNZ, cw);
#pragma unroll
    for (int j = 0; j < DNZ; ++j) {
      phi[j] = fmaf(cw[j], t, phi[j]);
      jph[j] = fmaf(cw[j], g, jph[j]);
    }
  }
#pragma unroll
  for (int j = 0; j < DNZ; ++j) { phi[j] = osum(phi[j]); jph[j] = osum(jph[j]); }

  // ---- I: t2e = Htau@e + Jtau@jph (partial); jte = Jtau@e (reduced) ----
  float t2e[DN], jte[DN];
#pragma unroll
  for (int n = 0; n < DN; ++n) { t2e[n] = 0.f; jte[n] = 0.f; }
#pragma unroll 2
  for (int kk = 0; kk < 4; ++kk) {
    const int k = 8 * kk + p;
    float wr[16]; row16h(sH + O_Wtau1 + k * DNZ, wr);
    float a = dot16r(wr, Tx) + sB[B_tau1 + k];
    float wp = dot16r(wr, phi);
    float v = dot16r(wr, e);
    float q = dot16r(wr, jph);
    float t = ftanh(a);
    float d = 1.f - t * t;
    float c = -2.f * t * d * wp;
    float g1 = fmaf(c, v, d * q);
    float g2 = d * v;
    float cw[16]; row16h(sH + O_Wtau2T + k * DN, cw);
#pragma unroll
    for (int n = 0; n < DN; ++n) {
      t2e[n] = fmaf(cw[n], g1, t2e[n]);
      jte[n] = fmaf(cw[n], g2, jte[n]);
    }
  }
#pragma unroll
  for (int n = 0; n < DN; ++n) jte[n] = osum(jte[n]);  // t2e stays partial

  // ---- J: t2e -= Jf @ jte (accumulate into partials, then reduce) ----
#pragma unroll 2
  for (int kk = 0; kk < 4; ++kk) {
    const int k = 8 * kk + p;
    float wr[16]; row16h(sH + O_Wf1 + k * DN, wr);
    float a = dot16r(wr, xh) + sB[B_f1 + k];
    float gj = dot16r(wr, jte);
    float t = ftanh(a);
    float g = (1.f - t * t) * gj;
    float cw[16]; row16h(sH + O_Wf2T + k * DN, cw);
#pragma unroll
    for (int n = 0; n < DN; ++n) t2e[n] = fmaf(-cw[n], g, t2e[n]);
  }
#pragma unroll
  for (int n = 0; n < DN; ++n) t2e[n] = osum(t2e[n]);

  // ---- K: loss (lane-owned n = 8nn+p via osel8, octet reduce) ----
  float ss = 0.f;
#pragma unroll
  for (int nn = 0; nn < 2; ++nn) {
    float tsel = osel8(t2e[8 * nn + 0], t2e[8 * nn + 1], t2e[8 * nn + 2], t2e[8 * nn + 3],
                       t2e[8 * nn + 4], t2e[8 * nn + 5], t2e[8 * nn + 6], t2e[8 * nn + 7], p);
    float r = fmaf(sv[nn], sdot, usel[nn]) - tsel;
    ss = fmaf(r, r, ss);
  }
  ss = osum(ss);
  float loss = sqrtf(ss);  // same on all 8 octet lanes

  // wave reduce across octets: offsets >=8 pair distinct octets -> each
  // octet's loss counted exactly once; wave sum = 8 sample losses.
#pragma unroll
  for (int off = 8; off < 64; off <<= 1) loss += __shfl_xor(loss, off);

  // block reduce: 4 waves (32 samples) -> ONE PLAIN STORE per block (no atomic)
  if ((tid & 63) == 0) wsum[tid >> 6] = loss;
  __syncthreads();
  if (tid == 0) part[blockIdx.x] = wsum[0] + wsum[1] + wsum[2] + wsum[3];
}

// second stage: reduce NBLK=512 partials -> out[0]
__global__ __launch_bounds__(256, 1) void reduce_kernel(const float* __restrict__ part,
                                                        float* __restrict__ out) {
  const int tid = threadIdx.x;
  float v = part[tid] + part[tid + 256];
#pragma unroll
  for (int off = 1; off < 64; off <<= 1) v += __shfl_xor(v, off);
  __shared__ float w[4];
  if ((tid & 63) == 0) w[tid >> 6] = v;
  __syncthreads();
  if (tid == 0) out[0] = (w[0] + w[1] + w[2] + w[3]) * (1.0f / (float)DB);
}

extern "C" void kernel_launch(void* const* d_in, const int* in_sizes, int n_in,
                              void* d_out, int out_size, void* d_ws, size_t ws_size,
                              hipStream_t stream) {
  const float* x_batch = (const float*)d_in[0];
  const float* e_batch = (const float*)d_in[1];
  const float* Wf1 = (const float*)d_in[2];
  const float* bf1 = (const float*)d_in[3];
  const float* Wf2 = (const float*)d_in[4];
  const float* Wh1 = (const float*)d_in[5];
  const float* bh1 = (const float*)d_in[6];
  const float* Wh2 = (const float*)d_in[7];
  const float* WT1 = (const float*)d_in[8];
  const float* bT1 = (const float*)d_in[9];
  const float* WT2 = (const float*)d_in[10];
  const float* Wtau1 = (const float*)d_in[11];
  const float* btau1 = (const float*)d_in[12];
  const float* Wtau2 = (const float*)d_in[13];
  const float* Wpsi1 = (const float*)d_in[14];
  const float* bpsi1 = (const float*)d_in[15];
  const float* Wpsi2 = (const float*)d_in[16];
  const float* WP = (const float*)d_in[17];

  float* part = (float*)d_ws;  // NBLK floats, fully rewritten every call
  loss_kernel<<<NBLK, 256, 0, stream>>>(
      x_batch, e_batch, Wf1, bf1, Wf2, Wh1, bh1, Wh2, WT1, bT1, WT2,
      Wtau1, btau1, Wtau2, Wpsi1, bpsi1, Wpsi2, WP, part);
  reduce_kernel<<<1, 256, 0, stream>>>(part, (float*)d_out);
}

// Round 10
// 20.600 us; speedup vs baseline: 2.4758x; 1.0638x over previous
//
#include <hip/hip_runtime.h>
#include <math.h>

#define DN 16
#define DNZ 16
#define DOUT 8
#define DH 32
#define DB 16384
#define RINV 10.0f
#define DPSI 24  // NZ+OUT
#define NBLK (DB / 32)  // 512 blocks

// ---- LDS layout (floats); second-layer weights TRANSPOSED [k][m] ----
#define O_WT1    0      // 32x16
#define O_WT2T   512    // 32x16
#define O_Wtau1  1024   // 32x16
#define O_Wtau2T 1536   // 32x16
#define O_Wh1    2048   // 32x16
#define O_Wh2T   2560   // 32x8
#define O_Wpsi1  2816   // 32x24
#define O_Wpsi2T 3584   // 32x16
#define O_Wf1    4096   // 32x16
#define O_Wf2T   4608   // 32x16
#define O_WP     5120   // 16x16
#define O_bT1    5376
#define O_btau1  5408
#define O_bh1    5440
#define O_bpsi1  5472
#define O_bf1    5504
#define LDS_FLOATS 5536

typedef __attribute__((ext_vector_type(2))) float f2;

__device__ __forceinline__ f2 pkfma(f2 a, f2 b, f2 c) {
  return __builtin_elementwise_fma(a, b, c);  // -> v_pk_fma_f32 on gfx950
}

// tanh(x) = 1 - 2/(1+exp(2x))
__device__ __forceinline__ float ftanh(float v) {
  float ex = __builtin_amdgcn_exp2f(v * 2.885390081777926815f);
  float r = __builtin_amdgcn_rcpf(1.0f + ex);
  return fmaf(-2.0f, r, 1.0f);
}

// DPP cross-lane: quad xor1 = 0xB1, quad xor2 = 0x4E, row_half_mirror = 0x141
__device__ __forceinline__ float qxor1(float v) {
  return __int_as_float(__builtin_amdgcn_mov_dpp(__float_as_int(v), 0xB1, 0xF, 0xF, true));
}
__device__ __forceinline__ float qxor2(float v) {
  return __int_as_float(__builtin_amdgcn_mov_dpp(__float_as_int(v), 0x4E, 0xF, 0xF, true));
}
__device__ __forceinline__ float hmir(float v) {
  return __int_as_float(__builtin_amdgcn_mov_dpp(__float_as_int(v), 0x141, 0xF, 0xF, true));
}
// sum over the 8-lane octet (pure DPP, full VALU rate)
__device__ __forceinline__ float osum(float v) {
  v += qxor1(v);
  v += qxor2(v);
  v += hmir(v);
  return v;
}
// per-lane select of one of 8 registers by p (7 cndmasks, no scratch)
__device__ __forceinline__ float osel8(float v0, float v1, float v2, float v3,
                                       float v4, float v5, float v6, float v7, int p) {
  float a = (p & 1) ? v1 : v0;
  float b = (p & 1) ? v3 : v2;
  float c = (p & 1) ? v5 : v4;
  float d = (p & 1) ? v7 : v6;
  float e0 = (p & 2) ? b : a;
  float e1 = (p & 2) ? d : c;
  return (p & 4) ? e1 : e0;
}

// packed dots: 16-dot = 8 pk_fma + horiz; 8-dot = 4 pk_fma + horiz
__device__ __forceinline__ float dot16p(const f2* __restrict__ w, const f2* __restrict__ v) {
  f2 a0 = {0.f, 0.f}, a1 = {0.f, 0.f};
#pragma unroll
  for (int j = 0; j < 4; ++j) {
    a0 = pkfma(w[j], v[j], a0);
    a1 = pkfma(w[j + 4], v[j + 4], a1);
  }
  f2 s = a0 + a1;
  return s.x + s.y;
}
__device__ __forceinline__ float dot8p(const f2* __restrict__ w, const f2* __restrict__ v) {
  f2 a0 = {0.f, 0.f}, a1 = {0.f, 0.f};
#pragma unroll
  for (int j = 0; j < 2; ++j) {
    a0 = pkfma(w[j], v[j], a0);
    a1 = pkfma(w[j + 2], v[j + 2], a1);
  }
  f2 s = a0 + a1;
  return s.x + s.y;
}

__global__ __launch_bounds__(256, 2) void loss_kernel(
    const float* __restrict__ x_batch, const float* __restrict__ e_batch,
    const float* __restrict__ Wf1, const float* __restrict__ bf1, const float* __restrict__ Wf2,
    const float* __restrict__ Wh1, const float* __restrict__ bh1, const float* __restrict__ Wh2,
    const float* __restrict__ WT1, const float* __restrict__ bT1, const float* __restrict__ WT2,
    const float* __restrict__ Wtau1, const float* __restrict__ btau1, const float* __restrict__ Wtau2,
    const float* __restrict__ Wpsi1, const float* __restrict__ bpsi1, const float* __restrict__ Wpsi2,
    const float* __restrict__ WP,
    float* __restrict__ part) {
  __shared__ float sW[LDS_FLOATS];
  __shared__ float wsum[4];
  const int tid = threadIdx.x;

  // ---- staging (256 threads), fp32 ----
  {
#pragma unroll
    for (int r = 0; r < 2; ++r) sW[O_WT1 + r * 256 + tid] = WT1[r * 256 + tid];
#pragma unroll
    for (int r = 0; r < 2; ++r) sW[O_Wtau1 + r * 256 + tid] = Wtau1[r * 256 + tid];
#pragma unroll
    for (int r = 0; r < 2; ++r) sW[O_Wh1 + r * 256 + tid] = Wh1[r * 256 + tid];
#pragma unroll
    for (int r = 0; r < 3; ++r) sW[O_Wpsi1 + r * 256 + tid] = Wpsi1[r * 256 + tid];
#pragma unroll
    for (int r = 0; r < 2; ++r) sW[O_Wf1 + r * 256 + tid] = Wf1[r * 256 + tid];
    sW[O_WP + tid] = WP[tid];
    // transposed: global (M,32) idx -> [k][m]
#pragma unroll
    for (int r = 0; r < 2; ++r) {
      int idx = r * 256 + tid; int j = idx >> 5, k = idx & 31;
      sW[O_WT2T + k * DNZ + j] = WT2[idx];
    }
#pragma unroll
    for (int r = 0; r < 2; ++r) {
      int idx = r * 256 + tid; int j = idx >> 5, k = idx & 31;
      sW[O_Wtau2T + k * DN + j] = Wtau2[idx];
    }
#pragma unroll
    for (int r = 0; r < 2; ++r) {
      int idx = r * 256 + tid; int j = idx >> 5, k = idx & 31;
      sW[O_Wpsi2T + k * DNZ + j] = Wpsi2[idx];
    }
#pragma unroll
    for (int r = 0; r < 2; ++r) {
      int idx = r * 256 + tid; int j = idx >> 5, k = idx & 31;
      sW[O_Wf2T + k * DN + j] = Wf2[idx];
    }
    { int o = tid >> 5, k = tid & 31; sW[O_Wh2T + k * DOUT + o] = Wh2[tid]; }
    if (tid < 32) {
      sW[O_bT1 + tid] = bT1[tid];
      sW[O_btau1 + tid] = btau1[tid];
      sW[O_bh1 + tid] = bh1[tid];
      sW[O_bpsi1 + tid] = bpsi1[tid];
      sW[O_bf1 + tid] = bf1[tid];
    }
  }
  __syncthreads();

  const int p = tid & 7;                          // lane in octet
  const int sidx = blockIdx.x * 32 + (tid >> 3);  // sample (32 per block)

  // ---- load sample (replicated across octet; cache-served) ----
  f2 x2[8], e2[8];
  {
    const float4* xp = reinterpret_cast<const float4*>(x_batch + (size_t)sidx * DN);
    const float4* ep = reinterpret_cast<const float4*>(e_batch + (size_t)sidx * DNZ);
#pragma unroll
    for (int q = 0; q < 4; ++q) {
      float4 vx = xp[q], ve = ep[q];
      x2[2 * q] = f2{vx.x, vx.y}; x2[2 * q + 1] = f2{vx.z, vx.w};
      e2[2 * q] = f2{ve.x, ve.y}; e2[2 * q + 1] = f2{ve.z, ve.w};
    }
  }

  // ---- A: z = T(x) + e ----
  f2 z2[8];
#pragma unroll
  for (int j = 0; j < 8; ++j) z2[j] = f2{0.f, 0.f};
#pragma unroll 2
  for (int kk = 0; kk < 4; ++kk) {
    const int k = 8 * kk + p;
    const f2* wr = reinterpret_cast<const f2*>(sW + O_WT1 + k * DN);
    float t = ftanh(dot16p(wr, x2) + sW[O_bT1 + k]);
    const f2* cw = reinterpret_cast<const f2*>(sW + O_WT2T + k * DNZ);
    f2 tv = {t, t};
#pragma unroll
    for (int j = 0; j < 8; ++j) z2[j] = pkfma(cw[j], tv, z2[j]);
  }
#pragma unroll
  for (int j = 0; j < 8; ++j) {
    z2[j].x = osum(z2[j].x) + e2[j].x;
    z2[j].y = osum(z2[j].y) + e2[j].y;
  }

  // ---- B: xh = tau(z); x -> diff ----
  f2 xh2[8];
#pragma unroll
  for (int j = 0; j < 8; ++j) xh2[j] = f2{0.f, 0.f};
#pragma unroll 2
  for (int kk = 0; kk < 4; ++kk) {
    const int k = 8 * kk + p;
    const f2* wr = reinterpret_cast<const f2*>(sW + O_Wtau1 + k * DNZ);
    float t = ftanh(dot16p(wr, z2) + sW[O_btau1 + k]);
    const f2* cw = reinterpret_cast<const f2*>(sW + O_Wtau2T + k * DN);
    f2 tv = {t, t};
#pragma unroll
    for (int j = 0; j < 8; ++j) xh2[j] = pkfma(cw[j], tv, xh2[j]);
  }
#pragma unroll
  for (int j = 0; j < 8; ++j) {
    xh2[j].x = osum(xh2[j].x); xh2[j].y = osum(xh2[j].y);
    x2[j] -= xh2[j];  // x2 = diff
  }

  // ---- C+D fused: yh, dth, w8 (one pass over Wh1/Wh2T) ----
  f2 yh2[4], w82[4];
#pragma unroll
  for (int o = 0; o < 4; ++o) { yh2[o] = f2{0.f, 0.f}; w82[o] = f2{0.f, 0.f}; }
  float dth[4];
#pragma unroll 2
  for (int kk = 0; kk < 4; ++kk) {
    const int k = 8 * kk + p;
    const f2* wr = reinterpret_cast<const f2*>(sW + O_Wh1 + k * DN);
    float t = ftanh(dot16p(wr, xh2) + sW[O_bh1 + k]);
    float d = 1.f - t * t;
    dth[kk] = d;
    float g = dot16p(wr, x2) * d;  // x2 = diff
    const f2* cw = reinterpret_cast<const f2*>(sW + O_Wh2T + k * DOUT);
    f2 tv = {t, t}, gv = {g, g};
#pragma unroll
    for (int o = 0; o < 4; ++o) {
      yh2[o] = pkfma(cw[o], tv, yh2[o]);
      w82[o] = pkfma(cw[o], gv, w82[o]);
    }
  }
#pragma unroll
  for (int o = 0; o < 4; ++o) {
    yh2[o].x = osum(yh2[o].x); yh2[o].y = osum(yh2[o].y);
    w82[o].x = osum(w82[o].x) * RINV; w82[o].y = osum(w82[o].y) * RINV;
  }

  // ---- E: u = Wh1^T @ (dth ∘ (Wh2^T @ w8)) ----
  f2 u2[8];
#pragma unroll
  for (int n = 0; n < 8; ++n) u2[n] = f2{0.f, 0.f};
#pragma unroll 2
  for (int kk = 0; kk < 4; ++kk) {
    const int k = 8 * kk + p;
    const f2* cw = reinterpret_cast<const f2*>(sW + O_Wh2T + k * DOUT);
    float g = dot8p(cw, w82) * dth[kk];
    const f2* wr = reinterpret_cast<const f2*>(sW + O_Wh1 + k * DN);
    f2 gv = {g, g};
#pragma unroll
    for (int n = 0; n < 8; ++n) u2[n] = pkfma(wr[n], gv, u2[n]);
  }
#pragma unroll
  for (int n = 0; n < 8; ++n) { u2[n].x = osum(u2[n].x); u2[n].y = osum(u2[n].y); }

  // ---- F: sv (lane-owned n = 8nn+p), sdot; u gathered via osel8 ----
  float sv[2], usel[2];
  float sdp = 0.f;
#pragma unroll
  for (int nn = 0; nn < 2; ++nn) {
    const int n = 8 * nn + p;
    const f2* wr = reinterpret_cast<const f2*>(sW + O_WP + n * DN);
    sv[nn] = ftanh(dot16p(wr, xh2));
    usel[nn] = osel8(u2[4 * nn + 0].x, u2[4 * nn + 0].y, u2[4 * nn + 1].x, u2[4 * nn + 1].y,
                     u2[4 * nn + 2].x, u2[4 * nn + 2].y, u2[4 * nn + 3].x, u2[4 * nn + 3].y, p);
    sdp = fmaf(sv[nn], usel[nn], sdp);
  }
  const float sdot = osum(sdp);

  // ---- G: Tx = T(xh) ----
  f2 Tx2[8];
#pragma unroll
  for (int j = 0; j < 8; ++j) Tx2[j] = f2{0.f, 0.f};
#pragma unroll 2
  for (int kk = 0; kk < 4; ++kk) {
    const int k = 8 * kk + p;
    const f2* wr = reinterpret_cast<const f2*>(sW + O_WT1 + k * DN);
    float t = ftanh(dot16p(wr, xh2) + sW[O_bT1 + k]);
    const f2* cw = reinterpret_cast<const f2*>(sW + O_WT2T + k * DNZ);
    f2 tv = {t, t};
#pragma unroll
    for (int j = 0; j < 8; ++j) Tx2[j] = pkfma(cw[j], tv, Tx2[j]);
  }
#pragma unroll
  for (int j = 0; j < 8; ++j) { Tx2[j].x = osum(Tx2[j].x); Tx2[j].y = osum(Tx2[j].y); }

  // ---- H: phi = psi(Tx,yh); jph = Jphi @ e ----
  f2 phi2[8], jph2[8];
#pragma unroll
  for (int j = 0; j < 8; ++j) { phi2[j] = f2{0.f, 0.f}; jph2[j] = f2{0.f, 0.f}; }
#pragma unroll 2
  for (int kk = 0; kk < 4; ++kk) {
    const int k = 8 * kk + p;
    const f2* wr = reinterpret_cast<const f2*>(sW + O_Wpsi1 + k * DPSI);
    float t = ftanh(dot16p(wr, Tx2) + dot8p(wr + 8, yh2) + sW[O_bpsi1 + k]);
    float d = 1.f - t * t;
    float g = d * dot16p(wr, e2);
    const f2* cw = reinterpret_cast<const f2*>(sW + O_Wpsi2T + k * DNZ);
    f2 tv = {t, t}, gv = {g, g};
#pragma unroll
    for (int j = 0; j < 8; ++j) {
      phi2[j] = pkfma(cw[j], tv, phi2[j]);
      jph2[j] = pkfma(cw[j], gv, jph2[j]);
    }
  }
#pragma unroll
  for (int j = 0; j < 8; ++j) {
    phi2[j].x = osum(phi2[j].x); phi2[j].y = osum(phi2[j].y);
    jph2[j].x = osum(jph2[j].x); jph2[j].y = osum(jph2[j].y);
  }

  // ---- I: t2e = Htau@e + Jtau@jph (partial); jte = Jtau@e (reduced) ----
  f2 t2e2[8], jte2[8];
#pragma unroll
  for (int n = 0; n < 8; ++n) { t2e2[n] = f2{0.f, 0.f}; jte2[n] = f2{0.f, 0.f}; }
#pragma unroll 2
  for (int kk = 0; kk < 4; ++kk) {
    const int k = 8 * kk + p;
    const f2* wr = reinterpret_cast<const f2*>(sW + O_Wtau1 + k * DNZ);
    float a = dot16p(wr, Tx2) + sW[O_btau1 + k];
    float wp = dot16p(wr, phi2);
    float v = dot16p(wr, e2);
    float q = dot16p(wr, jph2);
    float t = ftanh(a);
    float d = 1.f - t * t;
    float c = -2.f * t * d * wp;
    float g1 = fmaf(c, v, d * q);
    float g2 = d * v;
    const f2* cw = reinterpret_cast<const f2*>(sW + O_Wtau2T + k * DN);
    f2 g1v = {g1, g1}, g2v = {g2, g2};
#pragma unroll
    for (int n = 0; n < 8; ++n) {
      t2e2[n] = pkfma(cw[n], g1v, t2e2[n]);
      jte2[n] = pkfma(cw[n], g2v, jte2[n]);
    }
  }
#pragma unroll
  for (int n = 0; n < 8; ++n) { jte2[n].x = osum(jte2[n].x); jte2[n].y = osum(jte2[n].y); }
  // t2e2 stays partial

  // ---- J: t2e -= Jf @ jte (accumulate into partials, then reduce) ----
#pragma unroll 2
  for (int kk = 0; kk < 4; ++kk) {
    const int k = 8 * kk + p;
    const f2* wr = reinterpret_cast<const f2*>(sW + O_Wf1 + k * DN);
    float a = dot16p(wr, xh2) + sW[O_bf1 + k];
    float gj = dot16p(wr, jte2);
    float t = ftanh(a);
    float g = -(1.f - t * t) * gj;
    const f2* cw = reinterpret_cast<const f2*>(sW + O_Wf2T + k * DN);
    f2 gv = {g, g};
#pragma unroll
    for (int n = 0; n < 8; ++n) t2e2[n] = pkfma(cw[n], gv, t2e2[n]);
  }
#pragma unroll
  for (int n = 0; n < 8; ++n) { t2e2[n].x = osum(t2e2[n].x); t2e2[n].y = osum(t2e2[n].y); }

  // ---- K: loss (lane-owned n = 8nn+p via osel8, octet reduce) ----
  float ss = 0.f;
#pragma unroll
  for (int nn = 0; nn < 2; ++nn) {
    float tsel = osel8(t2e2[4 * nn + 0].x, t2e2[4 * nn + 0].y, t2e2[4 * nn + 1].x, t2e2[4 * nn + 1].y,
                       t2e2[4 * nn + 2].x, t2e2[4 * nn + 2].y, t2e2[4 * nn + 3].x, t2e2[4 * nn + 3].y, p);
    float r = fmaf(sv[nn], sdot, usel[nn]) - tsel;
    ss = fmaf(r, r, ss);
  }
  ss = osum(ss);
  float loss = sqrtf(ss);  // same on all 8 octet lanes

  // wave reduce across octets: offsets >=8 pair distinct octets -> each
  // octet's loss counted exactly once; wave sum = 8 sample losses.
#pragma unroll
  for (int off = 8; off < 64; off <<= 1) loss += __shfl_xor(loss, off);

  // block reduce: 4 waves (32 samples) -> ONE PLAIN STORE per block (no atomic)
  if ((tid & 63) == 0) wsum[tid >> 6] = loss;
  __syncthreads();
  if (tid == 0) part[blockIdx.x] = wsum[0] + wsum[1] + wsum[2] + wsum[3];
}

// second stage: reduce NBLK=512 partials -> out[0]
__global__ __launch_bounds__(256, 1) void reduce_kernel(const float* __restrict__ part,
                                                        float* __restrict__ out) {
  const int tid = threadIdx.x;
  float v = part[tid] + part[tid + 256];
#pragma unroll
  for (int off = 1; off < 64; off <<= 1) v += __shfl_xor(v, off);
  __shared__ float w[4];
  if ((tid & 63) == 0) w[tid >> 6] = v;
  __syncthreads();
  if (tid == 0) out[0] = (w[0] + w[1] + w[2] + w[3]) * (1.0f / (float)DB);
}

extern "C" void kernel_launch(void* const* d_in, const int* in_sizes, int n_in,
                              void* d_out, int out_size, void* d_ws, size_t ws_size,
                              hipStream_t stream) {
  const float* x_batch = (const float*)d_in[0];
  const float* e_batch = (const float*)d_in[1];
  const float* Wf1 = (const float*)d_in[2];
  const float* bf1 = (const float*)d_in[3];
  const float* Wf2 = (const float*)d_in[4];
  const float* Wh1 = (const float*)d_in[5];
  const float* bh1 = (const float*)d_in[6];
  const float* Wh2 = (const float*)d_in[7];
  const float* WT1 = (const float*)d_in[8];
  const float* bT1 = (const float*)d_in[9];
  const float* WT2 = (const float*)d_in[10];
  const float* Wtau1 = (const float*)d_in[11];
  const float* btau1 = (const float*)d_in[12];
  const float* Wtau2 = (const float*)d_in[13];
  const float* Wpsi1 = (const float*)d_in[14];
  const float* bpsi1 = (const float*)d_in[15];
  const float* Wpsi2 = (const float*)d_in[16];
  const float* WP = (const float*)d_in[17];

  float* part = (float*)d_ws;  // NBLK floats, fully rewritten every call
  loss_kernel<<<NBLK, 256, 0, stream>>>(
      x_batch, e_batch, Wf1, bf1, Wf2, Wh1, bh1, Wh2, WT1, bT1, WT2,
      Wtau1, btau1, Wtau2, Wpsi1, bpsi1, Wpsi2, WP, part);
  reduce_kernel<<<1, 256, 0, stream>>>(part, (float*)d_out);
}

// Round 12
// 19.019 us; speedup vs baseline: 2.6817x; 1.0831x over previous
//
#include <hip/hip_runtime.h>
#include <math.h>

#define DN 16
#define DNZ 16
#define DOUT 8
#define DH 32
#define DB 16384
#define RINV 10.0f
#define DPSI 24  // NZ+OUT
#define NBLK (DB / 32)  // 512 blocks

// ---- fp16 LDS (row-dot side), offsets in halves ----
#define HO_WT1   0      // 32x16
#define HO_Wtau1 512    // 32x16
#define HO_Wh1   1024   // 32x16
#define HO_Wpsi1 1536   // 32x24
#define HO_Wf1   2304   // 32x16
#define HO_WP    2816   // 16x16
#define HO_Wh2T  3072   // 32x8
#define LDS_H    3328
// ---- fp32 LDS (column-update side + biases), offsets in floats ----
#define FO_WT2T   0     // 32x16
#define FO_Wtau2T 512   // 32x16
#define FO_Wpsi2T 1024  // 32x16
#define FO_Wf2T   1536  // 32x16
#define FO_Wh2T   2048  // 32x8
#define FO_Wh1    2304  // 32x16 (fp32 copy for stage-E updates)
#define FO_bT1    2816
#define FO_btau1  2848
#define FO_bh1    2880
#define FO_bpsi1  2912
#define FO_bf1    2944
#define LDS_F     2976

typedef __attribute__((ext_vector_type(2))) float f2;
typedef __attribute__((ext_vector_type(2))) _Float16 h2;

__device__ __forceinline__ f2 pkfma(f2 a, f2 b, f2 c) {
  return __builtin_elementwise_fma(a, b, c);  // v_pk_fma_f32
}

#if defined(__has_builtin)
#if __has_builtin(__builtin_amdgcn_fdot2)
#define HAS_FDOT2 1
#endif
#endif

__device__ __forceinline__ float hdot2(h2 a, h2 b, float c) {
#ifdef HAS_FDOT2
  return __builtin_amdgcn_fdot2(a, b, c, false);  // v_dot2_f32_f16
#else
  return fmaf((float)a.x, (float)b.x, fmaf((float)a.y, (float)b.y, c));
#endif
}
__device__ __forceinline__ h2 pkh(float a, float b) {
#if defined(__has_builtin) && __has_builtin(__builtin_amdgcn_cvt_pkrtz)
  return __builtin_bit_cast(h2, __builtin_amdgcn_cvt_pkrtz(a, b));  // v_cvt_pkrtz_f16_f32
#else
  h2 r; r.x = (_Float16)a; r.y = (_Float16)b; return r;
#endif
}
__device__ __forceinline__ h2 bc(unsigned u) { return __builtin_bit_cast(h2, u); }

// 16-dot: preloaded row (2 x uint4 = 8 half2) vs half2 activation array
__device__ __forceinline__ float hd16(uint4 ua, uint4 ub, const h2* __restrict__ v) {
  float a0 = 0.f, a1 = 0.f;
  a0 = hdot2(bc(ua.x), v[0], a0); a1 = hdot2(bc(ua.y), v[1], a1);
  a0 = hdot2(bc(ua.z), v[2], a0); a1 = hdot2(bc(ua.w), v[3], a1);
  a0 = hdot2(bc(ub.x), v[4], a0); a1 = hdot2(bc(ub.y), v[5], a1);
  a0 = hdot2(bc(ub.z), v[6], a0); a1 = hdot2(bc(ub.w), v[7], a1);
  return a0 + a1;
}
__device__ __forceinline__ float hd8(uint4 ua, const h2* __restrict__ v) {
  float a0 = 0.f, a1 = 0.f;
  a0 = hdot2(bc(ua.x), v[0], a0); a1 = hdot2(bc(ua.y), v[1], a1);
  a0 = hdot2(bc(ua.z), v[2], a0); a1 = hdot2(bc(ua.w), v[3], a1);
  return a0 + a1;
}

// tanh(x) = 1 - 2/(1+exp(2x))
__device__ __forceinline__ float ftanh(float v) {
  float ex = __builtin_amdgcn_exp2f(v * 2.885390081777926815f);
  float r = __builtin_amdgcn_rcpf(1.0f + ex);
  return fmaf(-2.0f, r, 1.0f);
}

// DPP: quad xor1 = 0xB1, quad xor2 = 0x4E, row_half_mirror = 0x141
__device__ __forceinline__ float qxor1(float v) {
  return __int_as_float(__builtin_amdgcn_mov_dpp(__float_as_int(v), 0xB1, 0xF, 0xF, true));
}
__device__ __forceinline__ float qxor2(float v) {
  return __int_as_float(__builtin_amdgcn_mov_dpp(__float_as_int(v), 0x4E, 0xF, 0xF, true));
}
__device__ __forceinline__ float hmir(float v) {
  return __int_as_float(__builtin_amdgcn_mov_dpp(__float_as_int(v), 0x141, 0xF, 0xF, true));
}
__device__ __forceinline__ float osum(float v) {
  v += qxor1(v);
  v += qxor2(v);
  v += hmir(v);
  return v;
}
__device__ __forceinline__ float osel8(float v0, float v1, float v2, float v3,
                                       float v4, float v5, float v6, float v7, int p) {
  float a = (p & 1) ? v1 : v0;
  float b = (p & 1) ? v3 : v2;
  float c = (p & 1) ? v5 : v4;
  float d = (p & 1) ? v7 : v6;
  float e0 = (p & 2) ? b : a;
  float e1 = (p & 2) ? d : c;
  return (p & 4) ? e1 : e0;
}

__global__ __launch_bounds__(256, 2) void loss_kernel(
    const float* __restrict__ x_batch, const float* __restrict__ e_batch,
    const float* __restrict__ Wf1, const float* __restrict__ bf1, const float* __restrict__ Wf2,
    const float* __restrict__ Wh1, const float* __restrict__ bh1, const float* __restrict__ Wh2,
    const float* __restrict__ WT1, const float* __restrict__ bT1, const float* __restrict__ WT2,
    const float* __restrict__ Wtau1, const float* __restrict__ btau1, const float* __restrict__ Wtau2,
    const float* __restrict__ Wpsi1, const float* __restrict__ bpsi1, const float* __restrict__ Wpsi2,
    const float* __restrict__ WP,
    float* __restrict__ part) {
  __shared__ __align__(16) _Float16 sHh[LDS_H];
  __shared__ __align__(16) float sF[LDS_F];
  __shared__ float wsum[4];
  const int tid = threadIdx.x;

  // ---- staging ----
  {
#pragma unroll
    for (int r = 0; r < 2; ++r) sHh[HO_WT1 + r * 256 + tid] = (_Float16)WT1[r * 256 + tid];
#pragma unroll
    for (int r = 0; r < 2; ++r) sHh[HO_Wtau1 + r * 256 + tid] = (_Float16)Wtau1[r * 256 + tid];
#pragma unroll
    for (int r = 0; r < 2; ++r) {
      float v = Wh1[r * 256 + tid];
      sHh[HO_Wh1 + r * 256 + tid] = (_Float16)v;
      sF[FO_Wh1 + r * 256 + tid] = v;
    }
#pragma unroll
    for (int r = 0; r < 3; ++r) sHh[HO_Wpsi1 + r * 256 + tid] = (_Float16)Wpsi1[r * 256 + tid];
#pragma unroll
    for (int r = 0; r < 2; ++r) sHh[HO_Wf1 + r * 256 + tid] = (_Float16)Wf1[r * 256 + tid];
    sHh[HO_WP + tid] = (_Float16)WP[tid];
    // transposed fp32 column matrices: global (M,32) idx -> [k][m]
#pragma unroll
    for (int r = 0; r < 2; ++r) {
      int idx = r * 256 + tid; int j = idx >> 5, k = idx & 31;
      sF[FO_WT2T + k * DNZ + j] = WT2[idx];
    }
#pragma unroll
    for (int r = 0; r < 2; ++r) {
      int idx = r * 256 + tid; int j = idx >> 5, k = idx & 31;
      sF[FO_Wtau2T + k * DN + j] = Wtau2[idx];
    }
#pragma unroll
    for (int r = 0; r < 2; ++r) {
      int idx = r * 256 + tid; int j = idx >> 5, k = idx & 31;
      sF[FO_Wpsi2T + k * DNZ + j] = Wpsi2[idx];
    }
#pragma unroll
    for (int r = 0; r < 2; ++r) {
      int idx = r * 256 + tid; int j = idx >> 5, k = idx & 31;
      sF[FO_Wf2T + k * DN + j] = Wf2[idx];
    }
    {
      int o = tid >> 5, k = tid & 31;
      float v = Wh2[tid];
      sF[FO_Wh2T + k * DOUT + o] = v;
      sHh[HO_Wh2T + k * DOUT + o] = (_Float16)v;
    }
    if (tid < 32) {
      sF[FO_bT1 + tid] = bT1[tid];
      sF[FO_btau1 + tid] = btau1[tid];
      sF[FO_bh1 + tid] = bh1[tid];
      sF[FO_bpsi1 + tid] = bpsi1[tid];
      sF[FO_bf1 + tid] = bf1[tid];
    }
  }
  __syncthreads();

  const int p = tid & 7;                          // lane in octet
  const int sidx = blockIdx.x * 32 + (tid >> 3);  // sample

  // ---- load sample ----
  f2 x2[8], e2[8];
  h2 xinh[8], eh[8];
  {
    const float4* xp = reinterpret_cast<const float4*>(x_batch + (size_t)sidx * DN);
    const float4* ep = reinterpret_cast<const float4*>(e_batch + (size_t)sidx * DNZ);
#pragma unroll
    for (int q = 0; q < 4; ++q) {
      float4 vx = xp[q], ve = ep[q];
      x2[2 * q] = f2{vx.x, vx.y}; x2[2 * q + 1] = f2{vx.z, vx.w};
      e2[2 * q] = f2{ve.x, ve.y}; e2[2 * q + 1] = f2{ve.z, ve.w};
      xinh[2 * q] = pkh(vx.x, vx.y); xinh[2 * q + 1] = pkh(vx.z, vx.w);
      eh[2 * q] = pkh(ve.x, ve.y); eh[2 * q + 1] = pkh(ve.z, ve.w);
    }
  }

  // ---- A: z = T(x) + e ----
  h2 zh[8];
  {
    f2 z2[8];
#pragma unroll
    for (int j = 0; j < 8; ++j) z2[j] = f2{0.f, 0.f};
#pragma unroll 2
    for (int kk = 0; kk < 4; ++kk) {
      const int k = 8 * kk + p;
      const _Float16* row = sHh + HO_WT1 + k * DN;
      uint4 ua = *reinterpret_cast<const uint4*>(row);
      uint4 ub = *reinterpret_cast<const uint4*>(row + 8);
      float t = ftanh(hd16(ua, ub, xinh) + sF[FO_bT1 + k]);
      const f2* cw = reinterpret_cast<const f2*>(sF + FO_WT2T + k * DNZ);
      f2 tv = {t, t};
#pragma unroll
      for (int j = 0; j < 8; ++j) z2[j] = pkfma(cw[j], tv, z2[j]);
    }
#pragma unroll
    for (int j = 0; j < 8; ++j) {
      float zx = osum(z2[j].x) + e2[j].x;
      float zy = osum(z2[j].y) + e2[j].y;
      zh[j] = pkh(zx, zy);
    }
  }

  // ---- B: xh = tau(z); diff = x - xh ----
  h2 xhh[8], dfh[8];
  {
    f2 xh2[8];
#pragma unroll
    for (int n = 0; n < 8; ++n) xh2[n] = f2{0.f, 0.f};
#pragma unroll 2
    for (int kk = 0; kk < 4; ++kk) {
      const int k = 8 * kk + p;
      const _Float16* row = sHh + HO_Wtau1 + k * DNZ;
      uint4 ua = *reinterpret_cast<const uint4*>(row);
      uint4 ub = *reinterpret_cast<const uint4*>(row + 8);
      float t = ftanh(hd16(ua, ub, zh) + sF[FO_btau1 + k]);
      const f2* cw = reinterpret_cast<const f2*>(sF + FO_Wtau2T + k * DN);
      f2 tv = {t, t};
#pragma unroll
      for (int n = 0; n < 8; ++n) xh2[n] = pkfma(cw[n], tv, xh2[n]);
    }
#pragma unroll
    for (int n = 0; n < 8; ++n) {
      float xx = osum(xh2[n].x), xy = osum(xh2[n].y);
      xhh[n] = pkh(xx, xy);
      dfh[n] = pkh(x2[n].x - xx, x2[n].y - xy);
    }
  }

  // ---- C+D fused: yh, dth, w8 ----
  h2 yhh[4], w8h[4];
  float dth[4];
  {
    f2 yh2[4], w82[4];
#pragma unroll
    for (int o = 0; o < 4; ++o) { yh2[o] = f2{0.f, 0.f}; w82[o] = f2{0.f, 0.f}; }
#pragma unroll 2
    for (int kk = 0; kk < 4; ++kk) {
      const int k = 8 * kk + p;
      const _Float16* row = sHh + HO_Wh1 + k * DN;
      uint4 ua = *reinterpret_cast<const uint4*>(row);
      uint4 ub = *reinterpret_cast<const uint4*>(row + 8);
      float t = ftanh(hd16(ua, ub, xhh) + sF[FO_bh1 + k]);
      float d = 1.f - t * t;
      dth[kk] = d;
      float g = hd16(ua, ub, dfh) * d;
      const f2* cw = reinterpret_cast<const f2*>(sF + FO_Wh2T + k * DOUT);
      f2 tv = {t, t}, gv = {g, g};
#pragma unroll
      for (int o = 0; o < 4; ++o) {
        yh2[o] = pkfma(cw[o], tv, yh2[o]);
        w82[o] = pkfma(cw[o], gv, w82[o]);
      }
    }
#pragma unroll
    for (int o = 0; o < 4; ++o) {
      yhh[o] = pkh(osum(yh2[o].x), osum(yh2[o].y));
      w8h[o] = pkh(osum(w82[o].x) * RINV, osum(w82[o].y) * RINV);
    }
  }

  // ---- E: u = Wh1^T @ (dth ∘ (Wh2^T @ w8)) ----
  f2 u2[8];
#pragma unroll
  for (int n = 0; n < 8; ++n) u2[n] = f2{0.f, 0.f};
#pragma unroll 2
  for (int kk = 0; kk < 4; ++kk) {
    const int k = 8 * kk + p;
    uint4 ua = *reinterpret_cast<const uint4*>(sHh + HO_Wh2T + k * DOUT);
    float g = hd8(ua, w8h) * dth[kk];
    const f2* wr = reinterpret_cast<const f2*>(sF + FO_Wh1 + k * DN);
    f2 gv = {g, g};
#pragma unroll
    for (int n = 0; n < 8; ++n) u2[n] = pkfma(wr[n], gv, u2[n]);
  }
#pragma unroll
  for (int n = 0; n < 8; ++n) { u2[n].x = osum(u2[n].x); u2[n].y = osum(u2[n].y); }

  // ---- F: sv (lane-owned n = 8nn+p), sdot ----
  float sv[2], usel[2];
  float sdp = 0.f;
#pragma unroll
  for (int nn = 0; nn < 2; ++nn) {
    const int n = 8 * nn + p;
    const _Float16* row = sHh + HO_WP + n * DN;
    uint4 ua = *reinterpret_cast<const uint4*>(row);
    uint4 ub = *reinterpret_cast<const uint4*>(row + 8);
    sv[nn] = ftanh(hd16(ua, ub, xhh));
    usel[nn] = osel8(u2[4 * nn + 0].x, u2[4 * nn + 0].y, u2[4 * nn + 1].x, u2[4 * nn + 1].y,
                     u2[4 * nn + 2].x, u2[4 * nn + 2].y, u2[4 * nn + 3].x, u2[4 * nn + 3].y, p);
    sdp = fmaf(sv[nn], usel[nn], sdp);
  }
  const float sdot = osum(sdp);

  // ---- G: Tx = T(xh) ----
  h2 Txh[8];
  {
    f2 Tx2[8];
#pragma unroll
    for (int j = 0; j < 8; ++j) Tx2[j] = f2{0.f, 0.f};
#pragma unroll 2
    for (int kk = 0; kk < 4; ++kk) {
      const int k = 8 * kk + p;
      const _Float16* row = sHh + HO_WT1 + k * DN;
      uint4 ua = *reinterpret_cast<const uint4*>(row);
      uint4 ub = *reinterpret_cast<const uint4*>(row + 8);
      float t = ftanh(hd16(ua, ub, xhh) + sF[FO_bT1 + k]);
      const f2* cw = reinterpret_cast<const f2*>(sF + FO_WT2T + k * DNZ);
      f2 tv = {t, t};
#pragma unroll
      for (int j = 0; j < 8; ++j) Tx2[j] = pkfma(cw[j], tv, Tx2[j]);
    }
#pragma unroll
    for (int j = 0; j < 8; ++j) Txh[j] = pkh(osum(Tx2[j].x), osum(Tx2[j].y));
  }

  // ---- H: phi = psi(Tx,yh); jph = Jphi @ e ----
  h2 phih[8], jphh[8];
  {
    f2 phi2[8], jph2[8];
#pragma unroll
    for (int j = 0; j < 8; ++j) { phi2[j] = f2{0.f, 0.f}; jph2[j] = f2{0.f, 0.f}; }
#pragma unroll 2
    for (int kk = 0; kk < 4; ++kk) {
      const int k = 8 * kk + p;
      const _Float16* row = sHh + HO_Wpsi1 + k * DPSI;
      uint4 ua = *reinterpret_cast<const uint4*>(row);
      uint4 ub = *reinterpret_cast<const uint4*>(row + 8);
      uint4 uc = *reinterpret_cast<const uint4*>(row + 16);
      float t = ftanh(hd16(ua, ub, Txh) + hd8(uc, yhh) + sF[FO_bpsi1 + k]);
      float d = 1.f - t * t;
      float g = d * hd16(ua, ub, eh);
      const f2* cw = reinterpret_cast<const f2*>(sF + FO_Wpsi2T + k * DNZ);
      f2 tv = {t, t}, gv = {g, g};
#pragma unroll
      for (int j = 0; j < 8; ++j) {
        phi2[j] = pkfma(cw[j], tv, phi2[j]);
        jph2[j] = pkfma(cw[j], gv, jph2[j]);
      }
    }
#pragma unroll
    for (int j = 0; j < 8; ++j) {
      phih[j] = pkh(osum(phi2[j].x), osum(phi2[j].y));
      jphh[j] = pkh(osum(jph2[j].x), osum(jph2[j].y));
    }
  }

  // ---- I: t2e = Htau@e + Jtau@jph (partial); jte = Jtau@e ----
  f2 t2e2[8];
  h2 jteh[8];
#pragma unroll
  for (int n = 0; n < 8; ++n) t2e2[n] = f2{0.f, 0.f};
  {
    f2 jte2[8];
#pragma unroll
    for (int n = 0; n < 8; ++n) jte2[n] = f2{0.f, 0.f};
#pragma unroll 2
    for (int kk = 0; kk < 4; ++kk) {
      const int k = 8 * kk + p;
      const _Float16* row = sHh + HO_Wtau1 + k * DNZ;
      uint4 ua = *reinterpret_cast<const uint4*>(row);
      uint4 ub = *reinterpret_cast<const uint4*>(row + 8);
      float a = hd16(ua, ub, Txh) + sF[FO_btau1 + k];
      float wp = hd16(ua, ub, phih);
      float v = hd16(ua, ub, eh);
      float q = hd16(ua, ub, jphh);
      float t = ftanh(a);
      float d = 1.f - t * t;
      float c = -2.f * t * d * wp;
      float g1 = fmaf(c, v, d * q);
      float g2 = d * v;
      const f2* cw = reinterpret_cast<const f2*>(sF + FO_Wtau2T + k * DN);
      f2 g1v = {g1, g1}, g2v = {g2, g2};
#pragma unroll
      for (int n = 0; n < 8; ++n) {
        t2e2[n] = pkfma(cw[n], g1v, t2e2[n]);
        jte2[n] = pkfma(cw[n], g2v, jte2[n]);
      }
    }
#pragma unroll
    for (int n = 0; n < 8; ++n) jteh[n] = pkh(osum(jte2[n].x), osum(jte2[n].y));
  }

  // ---- J: t2e -= Jf @ jte ----
#pragma unroll 2
  for (int kk = 0; kk < 4; ++kk) {
    const int k = 8 * kk + p;
    const _Float16* row = sHh + HO_Wf1 + k * DN;
    uint4 ua = *reinterpret_cast<const uint4*>(row);
    uint4 ub = *reinterpret_cast<const uint4*>(row + 8);
    float a = hd16(ua, ub, xhh) + sF[FO_bf1 + k];
    float gj = hd16(ua, ub, jteh);
    float t = ftanh(a);
    float g = -(1.f - t * t) * gj;
    const f2* cw = reinterpret_cast<const f2*>(sF + FO_Wf2T + k * DN);
    f2 gv = {g, g};
#pragma unroll
    for (int n = 0; n < 8; ++n) t2e2[n] = pkfma(cw[n], gv, t2e2[n]);
  }
#pragma unroll
  for (int n = 0; n < 8; ++n) { t2e2[n].x = osum(t2e2[n].x); t2e2[n].y = osum(t2e2[n].y); }

  // ---- K: loss ----
  float ss = 0.f;
#pragma unroll
  for (int nn = 0; nn < 2; ++nn) {
    float tsel = osel8(t2e2[4 * nn + 0].x, t2e2[4 * nn + 0].y, t2e2[4 * nn + 1].x, t2e2[4 * nn + 1].y,
                       t2e2[4 * nn + 2].x, t2e2[4 * nn + 2].y, t2e2[4 * nn + 3].x, t2e2[4 * nn + 3].y, p);
    float r = fmaf(sv[nn], sdot, usel[nn]) - tsel;
    ss = fmaf(r, r, ss);
  }
  ss = osum(ss);
  float loss = sqrtf(ss);

#pragma unroll
  for (int off = 8; off < 64; off <<= 1) loss += __shfl_xor(loss, off);

  if ((tid & 63) == 0) wsum[tid >> 6] = loss;
  __syncthreads();
  if (tid == 0) part[blockIdx.x] = wsum[0] + wsum[1] + wsum[2] + wsum[3];
}

// second stage: reduce NBLK=512 partials -> out[0]; single wave
__global__ __launch_bounds__(64, 1) void reduce_kernel(const float* __restrict__ part,
                                                       float* __restrict__ out) {
  const int tid = threadIdx.x;
  float v = 0.f;
#pragma unroll
  for (int i = 0; i < NBLK / 64; ++i) v += part[tid + 64 * i];
#pragma unroll
  for (int off = 1; off < 64; off <<= 1) v += __shfl_xor(v, off);
  if (tid == 0) out[0] = v * (1.0f / (float)DB);
}

extern "C" void kernel_launch(void* const* d_in, const int* in_sizes, int n_in,
                              void* d_out, int out_size, void* d_ws, size_t ws_size,
                              hipStream_t stream) {
  const float* x_batch = (const float*)d_in[0];
  const float* e_batch = (const float*)d_in[1];
  const float* Wf1 = (const float*)d_in[2];
  const float* bf1 = (const float*)d_in[3];
  const float* Wf2 = (const float*)d_in[4];
  const float* Wh1 = (const float*)d_in[5];
  const float* bh1 = (const float*)d_in[6];
  const float* Wh2 = (const float*)d_in[7];
  const float* WT1 = (const float*)d_in[8];
  const float* bT1 = (const float*)d_in[9];
  const float* WT2 = (const float*)d_in[10];
  const float* Wtau1 = (const float*)d_in[11];
  const float* btau1 = (const float*)d_in[12];
  const float* Wtau2 = (const float*)d_in[13];
  const float* Wpsi1 = (const float*)d_in[14];
  const float* bpsi1 = (const float*)d_in[15];
  const float* Wpsi2 = (const float*)d_in[16];
  const float* WP = (const float*)d_in[17];

  float* part = (float*)d_ws;  // NBLK floats, fully rewritten every call
  loss_kernel<<<NBLK, 256, 0, stream>>>(
      x_batch, e_batch, Wf1, bf1, Wf2, Wh1, bh1, Wh2, WT1, bT1, WT2,
      Wtau1, btau1, Wtau2, Wpsi1, bpsi1, Wpsi2, WP, part);
  reduce_kernel<<<1, 64, 0, stream>>>(part, (float*)d_out);
}

// Round 13
// 11.998 us; speedup vs baseline: 4.2510x; 1.5852x over previous
//
#include <hip/hip_runtime.h>
#include <math.h>

#define DN 16
#define DOUT 8
#define DH 32
#define DB 16384
#define RINV 10.0f
#define NBLK 256  // 256 blocks x 4 waves x 16 samples = 16384

typedef __attribute__((ext_vector_type(4))) float f4;
typedef __attribute__((ext_vector_type(4))) _Float16 h4;

__device__ __forceinline__ f4 mfma(h4 a, h4 b, f4 c) {
  return __builtin_amdgcn_mfma_f32_16x16x16f16(a, b, c, 0, 0, 0);
}
__device__ __forceinline__ unsigned pk2(float a, float b) {
  return __builtin_bit_cast(unsigned, __builtin_amdgcn_cvt_pkrtz(a, b));
}
__device__ __forceinline__ h4 mkh4(f4 c) {
  uint2 u; u.x = pk2(c.x, c.y); u.y = pk2(c.z, c.w);
  return __builtin_bit_cast(h4, u);
}
__device__ __forceinline__ float ftanh(float v) {
  float ex = __builtin_amdgcn_exp2f(v * 2.885390081777926815f);
  float r = __builtin_amdgcn_rcpf(1.0f + ex);
  return fmaf(-2.0f, r, 1.0f);
}
__device__ __forceinline__ f4 tanh4(f4 v) {
  f4 r; r.x = ftanh(v.x); r.y = ftanh(v.y); r.z = ftanh(v.z); r.w = ftanh(v.w);
  return r;
}

// Fragment layouts for mfma_f32_16x16x16_f16 (lane l, j=0..3):
//   A: row = l&15,        k   = 4*(l>>4)+j
//   B: col = l&15,        k   = 4*(l>>4)+j
//   C/D: col = l&15,      row = 4*(l>>4)+j   [verified m89]
// => C/D layout == B layout: tanh'd outputs feed the next MFMA directly.

__global__ __launch_bounds__(256, 1) void loss_kernel(
    const float* __restrict__ x_batch, const float* __restrict__ e_batch,
    const float* __restrict__ Wf1, const float* __restrict__ bf1, const float* __restrict__ Wf2,
    const float* __restrict__ Wh1, const float* __restrict__ bh1, const float* __restrict__ Wh2,
    const float* __restrict__ WT1, const float* __restrict__ bT1, const float* __restrict__ WT2,
    const float* __restrict__ Wtau1, const float* __restrict__ btau1, const float* __restrict__ Wtau2,
    const float* __restrict__ Wpsi1, const float* __restrict__ bpsi1, const float* __restrict__ Wpsi2,
    const float* __restrict__ WP,
    float* __restrict__ part) {
  __shared__ float wsum[4];
  const int tid = threadIdx.x;
  const int l = tid & 63;
  const int r = l & 15, g = l >> 4;
  const int wid = blockIdx.x * 4 + (tid >> 6);
  const int s0 = wid * 16;
  const f4 zf = {0.f, 0.f, 0.f, 0.f};
  const f4 one = {1.f, 1.f, 1.f, 1.f};

  // ---- weight A-fragments (registers; identical across waves -> L2 broadcast) ----
  h4 A_T1[2], A_T2[2], A_tau1[2], A_tau2[2], A_h1[2], A_h2[2];
  h4 A_ps1a[2], A_ps1b[2], A_psi2[2], A_f1[2], A_f2[2], A_WP;
  h4 A_h1T[2], A_h2T[2];
#pragma unroll
  for (int mt = 0; mt < 2; ++mt) {  // M-tiles (rows r+16*mt) of 32xK row-major
    A_T1[mt]   = mkh4(*(const f4*)(WT1   + (r + 16 * mt) * DN + 4 * g));
    A_tau1[mt] = mkh4(*(const f4*)(Wtau1 + (r + 16 * mt) * DN + 4 * g));
    A_h1[mt]   = mkh4(*(const f4*)(Wh1   + (r + 16 * mt) * DN + 4 * g));
    A_f1[mt]   = mkh4(*(const f4*)(Wf1   + (r + 16 * mt) * DN + 4 * g));
    // psi1 (32x24): kt0 = cols 0..15 ; kt1 = cols 16..23 (k>=8 zero)
    A_ps1a[mt] = mkh4(*(const f4*)(Wpsi1 + (r + 16 * mt) * 24 + 4 * g));
    A_ps1b[mt] = (g < 2) ? mkh4(*(const f4*)(Wpsi1 + (r + 16 * mt) * 24 + 16 + 4 * g))
                         : mkh4(zf);
    // h2T (32x8): A[m][k] = Wh2[k][m], m = r+16mt, k = 4g+j < 8
    f4 t = zf;
    if (g < 2) {
      t.x = Wh2[(4 * g + 0) * DH + r + 16 * mt];
      t.y = Wh2[(4 * g + 1) * DH + r + 16 * mt];
      t.z = Wh2[(4 * g + 2) * DH + r + 16 * mt];
      t.w = Wh2[(4 * g + 3) * DH + r + 16 * mt];
    }
    A_h2T[mt] = mkh4(t);
  }
#pragma unroll
  for (int kt = 0; kt < 2; ++kt) {  // K-tiles of 16x32 row-major (row r, cols kt*16+4g..)
    A_T2[kt]   = mkh4(*(const f4*)(WT2   + r * DH + 16 * kt + 4 * g));
    A_tau2[kt] = mkh4(*(const f4*)(Wtau2 + r * DH + 16 * kt + 4 * g));
    A_psi2[kt] = mkh4(*(const f4*)(Wpsi2 + r * DH + 16 * kt + 4 * g));
    A_f2[kt]   = mkh4(*(const f4*)(Wf2   + r * DH + 16 * kt + 4 * g));
    // h2 (8x32 as A, M=16 pad rows>=8): A[m][k] = Wh2[r][16kt+4g+j], r<8
    A_h2[kt] = (r < 8) ? mkh4(*(const f4*)(Wh2 + r * DH + 16 * kt + 4 * g)) : mkh4(zf);
    // h1T (16x32): A[m][k] = Wh1[16kt+4g+j][m]
    f4 t;
    t.x = Wh1[(16 * kt + 4 * g + 0) * DN + r];
    t.y = Wh1[(16 * kt + 4 * g + 1) * DN + r];
    t.z = Wh1[(16 * kt + 4 * g + 2) * DN + r];
    t.w = Wh1[(16 * kt + 4 * g + 3) * DN + r];
    A_h1T[kt] = mkh4(t);
  }
  A_WP = mkh4(*(const f4*)(WP + r * DN + 4 * g));

  // biases as C-format f4: lane adds b[4g+j (+16*mt)]
  f4 bT1v[2], btau1v[2], bh1v[2], bpsi1v[2], bf1v[2];
#pragma unroll
  for (int mt = 0; mt < 2; ++mt) {
    bT1v[mt]   = *(const f4*)(bT1   + 16 * mt + 4 * g);
    btau1v[mt] = *(const f4*)(btau1 + 16 * mt + 4 * g);
    bh1v[mt]   = *(const f4*)(bh1   + 16 * mt + 4 * g);
    bpsi1v[mt] = *(const f4*)(bpsi1 + 16 * mt + 4 * g);
    bf1v[mt]   = *(const f4*)(bf1   + 16 * mt + 4 * g);
  }

  // ---- sample tiles: B-frag load pattern == C-format addition pattern (16x16) ----
  f4 xC = *(const f4*)(x_batch + (size_t)(s0 + r) * DN + 4 * g);
  f4 eC = *(const f4*)(e_batch + (size_t)(s0 + r) * DN + 4 * g);
  h4 xB = mkh4(xC), eB = mkh4(eC);

  // ---- A: z = T2 @ tanh(T1@x + b) + e ----
  f4 c0 = mfma(A_T1[0], xB, zf);
  f4 c1 = mfma(A_T1[1], xB, zf);
  h4 h0 = mkh4(tanh4(c0 + bT1v[0]));
  h4 h1 = mkh4(tanh4(c1 + bT1v[1]));
  f4 zc = mfma(A_T2[0], h0, zf);
  zc = mfma(A_T2[1], h1, zc);
  zc += eC;
  h4 zB = mkh4(zc);

  // ---- B: xh = tau(z); diff = x - xh ----
  c0 = mfma(A_tau1[0], zB, zf);
  c1 = mfma(A_tau1[1], zB, zf);
  h0 = mkh4(tanh4(c0 + btau1v[0]));
  h1 = mkh4(tanh4(c1 + btau1v[1]));
  f4 xhC = mfma(A_tau2[0], h0, zf);
  xhC = mfma(A_tau2[1], h1, xhC);
  h4 xhB = mkh4(xhC);
  h4 dfB = mkh4(xC - xhC);

  // ---- C: th, dth, yh ----
  c0 = mfma(A_h1[0], xhB, zf);
  c1 = mfma(A_h1[1], xhB, zf);
  f4 th0 = tanh4(c0 + bh1v[0]), th1 = tanh4(c1 + bh1v[1]);
  f4 dth0 = one - th0 * th0, dth1 = one - th1 * th1;
  f4 yhC = mfma(A_h2[0], mkh4(th0), zf);
  yhC = mfma(A_h2[1], mkh4(th1), yhC);  // rows 8..15 zero (A_h2 padded)
  h4 yhB = mkh4(yhC);

  // ---- D: w8 = RINV * Wh2 @ (dth o (Wh1 @ diff)) ----
  c0 = mfma(A_h1[0], dfB, zf);
  c1 = mfma(A_h1[1], dfB, zf);
  f4 w8C = mfma(A_h2[0], mkh4(dth0 * c0), zf);
  w8C = mfma(A_h2[1], mkh4(dth1 * c1), w8C);
  w8C *= RINV;
  h4 w8B = mkh4(w8C);  // k rows 8..15 zero

  // ---- E: u = Wh1^T @ (dth o (Wh2^T @ w8)) ----
  c0 = mfma(A_h2T[0], w8B, zf);
  c1 = mfma(A_h2T[1], w8B, zf);
  f4 uC = mfma(A_h1T[0], mkh4(dth0 * c0), zf);
  uC = mfma(A_h1T[1], mkh4(dth1 * c1), uC);

  // ---- F: s = tanh(WP@xh); term1 = u + s*(s.u) ----
  f4 svC = tanh4(mfma(A_WP, xhB, zf));
  float sd = svC.x * uC.x + svC.y * uC.y + svC.z * uC.z + svC.w * uC.w;
  sd += __shfl_xor(sd, 16);
  sd += __shfl_xor(sd, 32);
  f4 term1 = uC + svC * sd;

  // ---- G: Tx = T(xh) ----
  c0 = mfma(A_T1[0], xhB, zf);
  c1 = mfma(A_T1[1], xhB, zf);
  h0 = mkh4(tanh4(c0 + bT1v[0]));
  h1 = mkh4(tanh4(c1 + bT1v[1]));
  f4 TxC = mfma(A_T2[0], h0, zf);
  TxC = mfma(A_T2[1], h1, TxC);
  h4 TxB = mkh4(TxC);

  // ---- H: phi = psi(Tx,yh); jph = Jphi @ e ----
  c0 = mfma(A_ps1a[0], TxB, zf);
  c0 = mfma(A_ps1b[0], yhB, c0);
  c1 = mfma(A_ps1a[1], TxB, zf);
  c1 = mfma(A_ps1b[1], yhB, c1);
  f4 tp0 = tanh4(c0 + bpsi1v[0]), tp1 = tanh4(c1 + bpsi1v[1]);
  f4 dtp0 = one - tp0 * tp0, dtp1 = one - tp1 * tp1;
  f4 phiC = mfma(A_psi2[0], mkh4(tp0), zf);
  phiC = mfma(A_psi2[1], mkh4(tp1), phiC);
  h4 phiB = mkh4(phiC);
  c0 = mfma(A_ps1a[0], eB, zf);
  c1 = mfma(A_ps1a[1], eB, zf);
  f4 jphC = mfma(A_psi2[0], mkh4(dtp0 * c0), zf);
  jphC = mfma(A_psi2[1], mkh4(dtp1 * c1), jphC);
  h4 jphB = mkh4(jphC);

  // ---- I: t2e = Htau@e + Jtau@jph ; jte = Jtau@e ----
  f4 a0 = mfma(A_tau1[0], TxB, zf) + btau1v[0];
  f4 a1 = mfma(A_tau1[1], TxB, zf) + btau1v[1];
  f4 wp0 = mfma(A_tau1[0], phiB, zf), wp1 = mfma(A_tau1[1], phiB, zf);
  f4 vv0 = mfma(A_tau1[0], eB, zf), vv1 = mfma(A_tau1[1], eB, zf);
  f4 qq0 = mfma(A_tau1[0], jphB, zf), qq1 = mfma(A_tau1[1], jphB, zf);
  f4 t0 = tanh4(a0), t1 = tanh4(a1);
  f4 d0 = one - t0 * t0, d1 = one - t1 * t1;
  f4 cc0 = -2.0f * t0 * d0 * wp0, cc1 = -2.0f * t1 * d1 * wp1;
  f4 g1_0 = cc0 * vv0 + d0 * qq0, g1_1 = cc1 * vv1 + d1 * qq1;
  f4 g2_0 = d0 * vv0, g2_1 = d1 * vv1;
  f4 t2eC = mfma(A_tau2[0], mkh4(g1_0), zf);
  t2eC = mfma(A_tau2[1], mkh4(g1_1), t2eC);
  f4 jteC = mfma(A_tau2[0], mkh4(g2_0), zf);
  jteC = mfma(A_tau2[1], mkh4(g2_1), jteC);
  h4 jteB = mkh4(jteC);

  // ---- J: t2e -= Wf2 @ ((1-t^2) o (Wf1 @ jte)) ----
  a0 = mfma(A_f1[0], xhB, zf) + bf1v[0];
  a1 = mfma(A_f1[1], xhB, zf) + bf1v[1];
  f4 gj0 = mfma(A_f1[0], jteB, zf), gj1 = mfma(A_f1[1], jteB, zf);
  t0 = tanh4(a0);
  t1 = tanh4(a1);
  f4 gf0 = (one - t0 * t0) * gj0, gf1 = (one - t1 * t1) * gj1;
  f4 fC = mfma(A_f2[0], mkh4(gf0), zf);
  fC = mfma(A_f2[1], mkh4(gf1), fC);
  t2eC -= fC;

  // ---- K: loss ----
  f4 rr = term1 - t2eC;
  float ss = rr.x * rr.x + rr.y * rr.y + rr.z * rr.z + rr.w * rr.w;
  ss += __shfl_xor(ss, 16);
  ss += __shfl_xor(ss, 32);
  // ss now = per-column sum over all 16 rows; identical across the 4 row-groups
  float loss = sqrtf(ss) * 0.25f;  // each column counted 4x in the wave-sum below
#pragma unroll
  for (int off = 1; off < 64; off <<= 1) loss += __shfl_xor(loss, off);

  if (l == 0) wsum[tid >> 6] = loss;
  __syncthreads();
  if (tid == 0) part[blockIdx.x] = wsum[0] + wsum[1] + wsum[2] + wsum[3];
}

// reduce 256 partials -> out[0]
__global__ __launch_bounds__(64, 1) void reduce_kernel(const float* __restrict__ part,
                                                       float* __restrict__ out) {
  const int tid = threadIdx.x;
  float v = part[tid] + part[tid + 64] + part[tid + 128] + part[tid + 192];
#pragma unroll
  for (int off = 1; off < 64; off <<= 1) v += __shfl_xor(v, off);
  if (tid == 0) out[0] = v * (1.0f / (float)DB);
}

extern "C" void kernel_launch(void* const* d_in, const int* in_sizes, int n_in,
                              void* d_out, int out_size, void* d_ws, size_t ws_size,
                              hipStream_t stream) {
  const float* x_batch = (const float*)d_in[0];
  const float* e_batch = (const float*)d_in[1];
  const float* Wf1 = (const float*)d_in[2];
  const float* bf1 = (const float*)d_in[3];
  const float* Wf2 = (const float*)d_in[4];
  const float* Wh1 = (const float*)d_in[5];
  const float* bh1 = (const float*)d_in[6];
  const float* Wh2 = (const float*)d_in[7];
  const float* WT1 = (const float*)d_in[8];
  const float* bT1 = (const float*)d_in[9];
  const float* WT2 = (const float*)d_in[10];
  const float* Wtau1 = (const float*)d_in[11];
  const float* btau1 = (const float*)d_in[12];
  const float* Wtau2 = (const float*)d_in[13];
  const float* Wpsi1 = (const float*)d_in[14];
  const float* bpsi1 = (const float*)d_in[15];
  const float* Wpsi2 = (const float*)d_in[16];
  const float* WP = (const float*)d_in[17];

  float* part = (float*)d_ws;  // NBLK floats, fully rewritten every call
  loss_kernel<<<NBLK, 256, 0, stream>>>(
      x_batch, e_batch, Wf1, bf1, Wf2, Wh1, bh1, Wh2, WT1, bT1, WT2,
      Wtau1, btau1, Wtau2, Wpsi1, bpsi1, Wpsi2, WP, part);
  reduce_kernel<<<1, 64, 0, stream>>>(part, (float*)d_out);
}